// Round 4
// baseline (52328.192 us; speedup 1.0000x reference)
//
#include <hip/hip_runtime.h>

typedef unsigned int u32;
#define DEVI __device__ __forceinline__

// ---- JAX threefry2x32 (exact) ----
DEVI void tf2x32(u32 k0, u32 k1, u32 x0, u32 x1, u32& o0, u32& o1) {
  u32 ks2 = k0 ^ k1 ^ 0x1BD11BDAu;
  x0 += k0; x1 += k1;
#define TFR(r) { x0 += x1; x1 = (x1 << (r)) | (x1 >> (32 - (r))); x1 ^= x0; }
  TFR(13) TFR(15) TFR(26) TFR(6)
  x0 += k1; x1 += ks2 + 1u;
  TFR(17) TFR(29) TFR(16) TFR(24)
  x0 += ks2; x1 += k0 + 2u;
  TFR(13) TFR(15) TFR(26) TFR(6)
  x0 += k0; x1 += k1 + 3u;
  TFR(17) TFR(29) TFR(16) TFR(24)
  x0 += k1; x1 += ks2 + 4u;
  TFR(13) TFR(15) TFR(26) TFR(6)
  x0 += ks2; x1 += k0 + 5u;
#undef TFR
  o0 = x0; o1 = x1;
}

DEVI float jax_uniform(u32 k0, u32 k1, u32 idx) {
  u32 a, b; tf2x32(k0, k1, 0u, idx, a, b);
  u32 bits = a ^ b;
  return __uint_as_float((bits >> 9) | 0x3F800000u) - 1.0f;
}

DEVI float sigmoidf_(float x) { return 1.0f / (1.0f + expf(-x)); }

// coherent (agent-scope, L2-bypassing) scalar access for cross-block mutable state
DEVI float AL(const float* p) {
  return __hip_atomic_load((float*)p, __ATOMIC_RELAXED, __HIP_MEMORY_SCOPE_AGENT);
}
DEVI void AS(float* p, float v) {
  __hip_atomic_store(p, v, __ATOMIC_RELAXED, __HIP_MEMORY_SCOPE_AGENT);
}

// async global->LDS, 16B per lane (dest = wave-uniform base + lane*16)
typedef const __attribute__((address_space(1))) u32* gas1;
typedef __attribute__((address_space(3))) u32* las3;
DEVI void gl16(const float* g, float* l) {
  __builtin_amdgcn_global_load_lds((gas1)g, (las3)l, 16, 0, 0);
}
#define WAITV(N) asm volatile("s_waitcnt vmcnt(" #N ")" ::: "memory")

struct KArgs {
  const float* enc_key; const float* value;
  const int* labels; const int* seqlens; const int* sos;
  const float* w_emb; const float* b_emb;
  const float* w_ih0; const float* w_hh0; const float* b_ih0; const float* b_hh0;
  const float* w_ih1; const float* w_hh1; const float* b_ih1; const float* b_hh1;
  const float* w_ih2; const float* w_hh2; const float* b_ih2; const float* b_hh2;
  const float* w_fc; const float* b_fc;
  const float* w_mlp1; const float* b_mlp1;
  const float* w_mlp2; const float* b_mlp2;
  float* out; float* ws;
};

// ws offsets (floats)
#define OF_LS     0
#define OF_Y0     1048576
#define OF_XEMB   1052672
#define OF_HSB    5246976   // [3][2][512][64]
#define OF_CSB    5443584
#define OF_CTX    5640192   // [257][128][64]
#define OF_CTXQ   7745536   // [64][4][128]
#define OF_MSQ    7778304   // [64][4][2]
#define OF_QA     7778816   // [256][128][64]
#define OF_WFCT   9875968   // [512][128]
#define OF_BAR    9941504   // 4096 ints
#define OF_QBAR   9945600   // 1024 ints
#define WS_TOTAL  9946624

// two-level grid barrier, NO cache flush in fast mode (mutable data uses AL/AS)
DEVI void gridbar(int* bar, int& ep, bool flush) {
  WAITV(0);
  __syncthreads();
  if (threadIdx.x == 0) {
    if (flush) __threadfence();
    int g = (int)(blockIdx.x & 15);
    int old = __hip_atomic_fetch_add(bar + g * 64, 1, __ATOMIC_RELAXED, __HIP_MEMORY_SCOPE_AGENT);
    if (old == ep * 16 - 1) {
      int o2 = __hip_atomic_fetch_add(bar + 1024, 1, __ATOMIC_RELAXED, __HIP_MEMORY_SCOPE_AGENT);
      if (o2 == ep * 16 - 1) {
        #pragma unroll
        for (int gg = 0; gg < 16; ++gg)
          __hip_atomic_store(bar + 2048 + gg * 64, ep, __ATOMIC_RELAXED, __HIP_MEMORY_SCOPE_AGENT);
      }
    }
    while (__hip_atomic_load(bar + 2048 + g * 64, __ATOMIC_RELAXED, __HIP_MEMORY_SCOPE_AGENT) < ep)
      __builtin_amdgcn_s_sleep(2);
    if (flush) __threadfence();
  }
  __syncthreads();
  ++ep;
}

__global__ void bar_init_kernel(int* bar) {
  for (int i = 0; i < 10; ++i) {
    int idx = threadIdx.x + i * 512;
    if (idx < 5120) bar[idx] = 0;
  }
}

// B=64 TK=2048 TL=256 V=64 E=256 KV=128 H=512 MH=256
__global__ __launch_bounds__(512, 2) void dec_kernel(KArgs A) {
  const int blk = blockIdx.x;
  const int tid = threadIdx.x;
  const int lane = tid & 63;
  const int wv = tid >> 6;

  float* const LS   = A.ws + OF_LS;
  float* const Y0   = A.ws + OF_Y0;
  float* const XEMB = A.ws + OF_XEMB;
  float* const HSb  = A.ws + OF_HSB;
  float* const CSb  = A.ws + OF_CSB;
  float* const CTX  = A.ws + OF_CTX;
  float* const CTXQ = A.ws + OF_CTXQ;
  float* const MSQ  = A.ws + OF_MSQ;
  float* const QA   = A.ws + OF_QA;
  float* const WFCT = A.ws + OF_WFCT;
  int*   const bar  = (int*)(A.ws + OF_BAR);
  int*   const qbar = (int*)(A.ws + OF_QBAR);

  float* const out0 = A.out;              // y_hat [64][256][64]
  float* const out1 = A.out + 1048576;    // argmax as float [64][256]
  float* const out2 = A.out + 1064960;    // labels.T [64][256]
  float* const out3 = A.out + 1081344;    // labels_smoothed [64][256][64]
  float* const out4 = A.out + 2129920;    // attentions [64][2048][256]

  __shared__ __align__(16) float SMf[36992];   // 144.5 KB
  int ep = 1;

  const int bq = blk >> 2, ch = blk & 3;

  // ===== persistent K rows in registers: K[bq][ch*512+tid][0..127] =====
  float4 kr[32];
  {
    const float4* kp = (const float4*)(A.enc_key + (size_t)bq * 262144 + (size_t)(ch * 512 + tid) * 128);
    #pragma unroll
    for (int i = 0; i < 32; ++i) kr[i] = kp[i];
  }

  u32 KA0, KA1, KB0, KB1;
  tf2x32(0u, 42u, 0u, 0u, KA0, KA1);
  tf2x32(0u, 42u, 0u, 1u, KB0, KB1);

  // ===== Prologue role work =====
  if (blk <= 128) {
    int slot = blk * 512 + tid;
    int r = slot >> 2, q = slot & 3;
    if (r < 16448) {
      bool isY0 = (r >= 16384);
      int t = 0, b, label;
      u32 key0, key1, base;
      if (!isY0) {
        t = r >> 6; b = r & 63;
        label = A.labels[t * 64 + b];
        key0 = KA0; key1 = KA1; base = (u32)(r * 64);
      } else {
        b = r - 16384;
        label = A.sos[0];
        key0 = KB0; key1 = KB1; base = (u32)(b * 64);
      }
      float sv[16];
      float mx = -3.0e38f;
      #pragma unroll
      for (int j = 0; j < 16; ++j) {
        int v = (q << 4) + j;
        float u = jax_uniform(key0, key1, base + (u32)v);
        float inner = -logf(u + 1e-10f) + 1e-10f;
        float noise = -logf(inner);
        float s = noise + ((v == label) ? 1.0f : 0.0f);
        sv[j] = s; mx = fmaxf(mx, s);
      }
      mx = fmaxf(mx, __shfl_xor(mx, 1));
      mx = fmaxf(mx, __shfl_xor(mx, 2));
      float sum = 0.f;
      #pragma unroll
      for (int j = 0; j < 16; ++j) { sv[j] = expf(sv[j] - mx); sum += sv[j]; }
      sum += __shfl_xor(sum, 1);
      sum += __shfl_xor(sum, 2);
      float inv = 1.0f / sum;
      if (!isY0) {
        #pragma unroll
        for (int j = 0; j < 16; ++j) {
          int v = (q << 4) + j;
          float val = sv[j] * inv;
          LS[r * 64 + v] = val;
          out3[b * 16384 + t * 64 + v] = val;
        }
        if (q == 0) out2[b * 256 + t] = (float)label;
      } else {
        #pragma unroll
        for (int j = 0; j < 16; ++j) Y0[b * 64 + (q << 4) + j] = sv[j] * inv;
      }
    }
  } else if (blk <= 192) {
    #pragma unroll
    for (int i = 0; i < 2; ++i) {
      int idx = (blk - 129) * 1024 + tid + i * 512;
      int kv = idx >> 9, j = idx & 511;
      WFCT[j * 128 + kv] = A.w_fc[kv * 512 + j];
    }
  } else {
    // zero h/c + CTX[0]: contiguous 401408 floats at HSb
    for (int idx = (blk - 193) * 512 + tid; idx < 401408; idx += 63 * 512)
      HSb[idx] = 0.f;
  }
  gridbar(bar, ep, true);    // FLUSH: publish prologue writes

  // ===== P1: embeddings XEMB[t][e][b] =====
  {
    const int t = blk;
    const float* src = (t == 0) ? Y0 : (LS + (t - 1) * 4096);
    #pragma unroll
    for (int i = 0; i < 8; ++i) {
      int idx = tid + i * 512;
      SMf[(idx >> 6) * 65 + (idx & 63)] = src[idx];
    }
    __syncthreads();
    const int b = lane;
    float* dst = XEMB + t * 16384;
    #pragma unroll 1
    for (int e0 = 0; e0 < 32; ++e0) {
      int e = wv * 32 + e0;
      const float* we = A.w_emb + e * 64;
      float acc = A.b_emb[e];
      #pragma unroll 8
      for (int v = 0; v < 64; ++v) acc = fmaf(we[v], SMf[b * 65 + v], acc);
      dst[e * 64 + b] = acc;
    }
  }
  gridbar(bar, ep, true);    // FLUSH: publish XEMB

  const int lenb = A.seqlens[bq];

  // ===== main recurrence: 4 barriers/step, no cache flushes =====
  #pragma unroll 1
  for (int t = 0; t < 256; ++t) {
    const int p = t & 1;

    // ---- 3 LSTM layer phases: 8 rows/block, 8-wave K split, s_load weights ----
    #pragma unroll 1
    for (int l = 0; l < 3; ++l) {
      const int b = lane;
      const int j0 = blk * 2;
      int rowoff[8];
      #pragma unroll
      for (int r = 0; r < 8; ++r) rowoff[r] = (r >> 1) * 512 + j0 + (r & 1);
      float acc[8] = {0.f,0.f,0.f,0.f,0.f,0.f,0.f,0.f};

      if (l == 0) {
        const int kb = wv * 112, ke = kb + 112;
        const float* wih = A.w_ih0;
        const float* whh = A.w_hh0;
        const float* ctxt = CTX + t * 8192;
        const float* h0p  = HSb + (0 * 2 + p) * 32768;
        int e1 = ke < 256 ? ke : 256;
        #pragma unroll 8
        for (int k = kb; k < e1; ++k) {
          float xv = XEMB[t * 16384 + k * 64 + b];
          #pragma unroll
          for (int r = 0; r < 8; ++r) acc[r] = fmaf(wih[rowoff[r] * 384 + k], xv, acc[r]);
        }
        int c0 = kb > 256 ? kb : 256, c1 = ke < 384 ? ke : 384;
        #pragma unroll 16
        for (int k = c0; k < c1; ++k) {
          float xv = AL(ctxt + (k - 256) * 64 + b);
          #pragma unroll
          for (int r = 0; r < 8; ++r) acc[r] = fmaf(wih[rowoff[r] * 384 + k], xv, acc[r]);
        }
        int h0s = kb > 384 ? kb : 384;
        #pragma unroll 16
        for (int k = h0s; k < ke; ++k) {
          float xv = AL(h0p + (k - 384) * 64 + b);
          #pragma unroll
          for (int r = 0; r < 8; ++r) acc[r] = fmaf(whh[rowoff[r] * 512 + (k - 384)], xv, acc[r]);
        }
      } else {
        const int kb = wv * 128, ke = kb + 128;
        const float* wih = (l == 1) ? A.w_ih1 : A.w_ih2;
        const float* whh = (l == 1) ? A.w_hh1 : A.w_hh2;
        const float* hin = HSb + ((l - 1) * 2 + (p ^ 1)) * 32768;
        const float* hpr = HSb + (l * 2 + p) * 32768;
        int e1 = ke < 512 ? ke : 512;
        #pragma unroll 16
        for (int k = kb; k < e1; ++k) {
          float xv = AL(hin + k * 64 + b);
          #pragma unroll
          for (int r = 0; r < 8; ++r) acc[r] = fmaf(wih[rowoff[r] * 512 + k], xv, acc[r]);
        }
        int h1s = kb > 512 ? kb : 512;
        #pragma unroll 16
        for (int k = h1s; k < ke; ++k) {
          float xv = AL(hpr + (k - 512) * 64 + b);
          #pragma unroll
          for (int r = 0; r < 8; ++r) acc[r] = fmaf(whh[rowoff[r] * 512 + (k - 512)], xv, acc[r]);
        }
      }
      #pragma unroll
      for (int r = 0; r < 8; ++r) SMf[wv * 512 + r * 64 + b] = acc[r];
      __syncthreads();
      if (tid < 128) {
        const float *bih, *bhh;
        if (l == 0)      { bih = A.b_ih0; bhh = A.b_hh0; }
        else if (l == 1) { bih = A.b_ih1; bhh = A.b_hh1; }
        else             { bih = A.b_ih2; bhh = A.b_hh2; }
        int jj = tid >> 6, bb = tid & 63;
        int j = j0 + jj;
        float g4[4];
        #pragma unroll
        for (int g = 0; g < 4; ++g) {
          float s = 0.f;
          #pragma unroll
          for (int w2 = 0; w2 < 8; ++w2) s += SMf[w2 * 512 + (g * 2 + jj) * 64 + bb];
          int row = g * 512 + j;
          g4[g] = s + bih[row] + bhh[row];
        }
        float cprev = AL(CSb + (l * 2 + p) * 32768 + j * 64 + bb);
        float c2 = sigmoidf_(g4[1]) * cprev + sigmoidf_(g4[0]) * tanhf(g4[2]);
        AS(CSb + (l * 2 + (p ^ 1)) * 32768 + j * 64 + bb, c2);
        AS(HSb + (l * 2 + (p ^ 1)) * 32768 + j * 64 + bb, sigmoidf_(g4[3]) * tanhf(c2));
      }
      gridbar(bar, ep, false);
    }

    // ---- ATTN phase: block=(bq,ch); K from registers, V gl16-pipelined ----
    {
      float* VB  = SMf;            // 4 x 8192
      float* H2C = SMf + 32768;    // 512
      float* QP  = SMf + 33280;    // 512
      float* QV  = SMf + 33792;    // 128
      float* ZS  = SMf + 33920;    // 512
      float* MR  = SMf + 34432;    // 32
      float* PR  = SMf + 34464;    // 2048
      const float* vbase = A.value + (size_t)bq * 262144 + (size_t)ch * 65536;

      // h2 column load (asm, issued FIRST so WAITV(16) drains only it)
      float h2v;
      {
        const float* hp = HSb + (4 + (p ^ 1)) * 32768 + tid * 64 + bq;
        asm volatile("global_load_dword %0, %1, off sc0 sc1" : "=v"(h2v) : "v"(hp));
      }
      // issue V tiles 0..3 (4 gl16/wave each)
      #pragma unroll
      for (int n = 0; n < 4; ++n)
        #pragma unroll
        for (int i = 0; i < 4; ++i)
          gl16(vbase + (n * 64 + wv * 8 + 2 * i) * 128 + lane * 4,
               VB + n * 8192 + (wv * 8 + 2 * i) * 128);
      WAITV(16);
      __builtin_amdgcn_sched_barrier(0);
      H2C[tid] = h2v;
      __syncthreads();
      // q partials over j-quarters
      {
        int kv = tid & 127, jg = tid >> 7;
        const float* wf = WFCT + (jg * 128) * 128 + kv;
        float pa = 0.f;
        #pragma unroll 8
        for (int jl = 0; jl < 128; ++jl) pa = fmaf(wf[jl * 128], H2C[jg * 128 + jl], pa);
        QP[jg * 128 + kv] = pa;
      }
      __syncthreads();
      if (tid < 128) {
        float qv = A.b_fc[tid] + QP[tid] + QP[128 + tid] + QP[256 + tid] + QP[384 + tid];
        QV[tid] = qv;
        if (ch == 0) QA[t * 8192 + tid * 64 + bq] = qv;
      }
      __syncthreads();
      // energy from K registers + chunk softmax
      float m_ch, s_ch;
      {
        float e = 0.f;
        #pragma unroll
        for (int i = 0; i < 32; ++i) {
          float4 q4 = *(const float4*)&QV[i * 4];
          e = fmaf(kr[i].x, q4.x, e); e = fmaf(kr[i].y, q4.y, e);
          e = fmaf(kr[i].z, q4.z, e); e = fmaf(kr[i].w, q4.w, e);
        }
        float z = (ch * 512 + tid < lenb) ? e : 0.0f;   // energy * mask
        float mm = z;
        #pragma unroll
        for (int d = 1; d < 64; d <<= 1) mm = fmaxf(mm, __shfl_xor(mm, d));
        if (lane == 0) MR[wv] = mm;
        __syncthreads();
        mm = MR[0];
        #pragma unroll
        for (int i2 = 1; i2 < 8; ++i2) mm = fmaxf(mm, MR[i2]);
        m_ch = mm;
        float es = expf(z - mm);
        ZS[tid] = es;
        float ss = es;
        #pragma unroll
        for (int d = 1; d < 64; d <<= 1) ss += __shfl_xor(ss, d);
        if (lane == 0) MR[8 + wv] = ss;
        __syncthreads();
        ss = 0.f;
        #pragma unroll
        for (int i2 = 0; i2 < 8; ++i2) ss += MR[8 + i2];
        s_ch = ss;
        if (tid == 0) {
          AS(MSQ + bq * 8 + ch * 2, m_ch);
          AS(MSQ + bq * 8 + ch * 2 + 1, s_ch);
        }
      }
      // PV over 8 tiles of 64 t', 4 LDS buffers, counted vmcnt
      float c0 = 0.f, c1 = 0.f, c2 = 0.f, c3 = 0.f;
      const int kv4 = (tid & 31) * 4, tg = tid >> 5;
#define PVCONS(N) { const float* B = VB + ((N) & 3) * 8192; \
      _Pragma("unroll") for (int i = 0; i < 4; ++i) { \
        float a = ZS[(N) * 64 + tg * 4 + i]; \
        float4 v4 = *(const float4*)&B[(tg * 4 + i) * 128 + kv4]; \
        c0 = fmaf(a, v4.x, c0); c1 = fmaf(a, v4.y, c1); \
        c2 = fmaf(a, v4.z, c2); c3 = fmaf(a, v4.w, c3); } }
#define PVISSUE(N) { _Pragma("unroll") for (int i = 0; i < 4; ++i) \
        gl16(vbase + ((N) * 64 + wv * 8 + 2 * i) * 128 + lane * 4, \
             VB + ((N) & 3) * 8192 + (wv * 8 + 2 * i) * 128); }
      WAITV(12); __syncthreads(); PVCONS(0); __syncthreads(); PVISSUE(4);
      WAITV(12); __syncthreads(); PVCONS(1); __syncthreads(); PVISSUE(5);
      WAITV(12); __syncthreads(); PVCONS(2); __syncthreads(); PVISSUE(6);
      WAITV(12); __syncthreads(); PVCONS(3); __syncthreads(); PVISSUE(7);
      WAITV(8);  __syncthreads(); PVCONS(4);
      WAITV(4);  __syncthreads(); PVCONS(5);
      WAITV(0);  __syncthreads(); PVCONS(6); PVCONS(7);
#undef PVCONS
#undef PVISSUE
      PR[tg * 128 + kv4]     = c0;
      PR[tg * 128 + kv4 + 1] = c1;
      PR[tg * 128 + kv4 + 2] = c2;
      PR[tg * 128 + kv4 + 3] = c3;
      __syncthreads();
      float ownpart = 0.f;
      if (tid < 128) {
        float s = 0.f;
        #pragma unroll
        for (int g2 = 0; g2 < 16; ++g2) s += PR[g2 * 128 + tid];
        ownpart = s;
        AS(CTXQ + bq * 512 + ch * 128 + tid, s);
      }
      WAITV(0);
      __syncthreads();
      // quad-team micro-barrier (4 blocks of this batch)
      if (tid == 0) {
        int* qc = qbar + bq * 16;
        __hip_atomic_fetch_add(qc, 1, __ATOMIC_RELAXED, __HIP_MEMORY_SCOPE_AGENT);
        int tgt = (t + 1) * 4;
        while (__hip_atomic_load(qc, __ATOMIC_RELAXED, __HIP_MEMORY_SCOPE_AGENT) < tgt)
          __builtin_amdgcn_s_sleep(1);
      }
      __syncthreads();
      if (tid < 8) MR[16 + tid] = AL(MSQ + bq * 8 + tid);
      __syncthreads();
      float mall = fmaxf(fmaxf(MR[16], MR[18]), fmaxf(MR[20], MR[22]));
      float Z = MR[17] * expf(MR[16] - mall) + MR[19] * expf(MR[18] - mall)
              + MR[21] * expf(MR[20] - mall) + MR[23] * expf(MR[22] - mall);
      float invZ = 1.0f / Z;
      out4[(size_t)bq * 524288 + (size_t)(ch * 512 + tid) * 256 + t]
          = ZS[tid] * (expf(m_ch - mall) * invZ);
      if (ch == 0 && tid < 128) {
        float f0 = expf(MR[16] - mall) * invZ;
        float f1 = expf(MR[18] - mall) * invZ;
        float f2 = expf(MR[20] - mall) * invZ;
        float f3 = expf(MR[22] - mall) * invZ;
        float cx = ownpart * f0
                 + AL(CTXQ + bq * 512 + 128 + tid) * f1
                 + AL(CTXQ + bq * 512 + 256 + tid) * f2
                 + AL(CTXQ + bq * 512 + 384 + tid) * f3;
        AS(CTX + (t + 1) * 8192 + tid * 64 + bq, cx);
      }
    }
    gridbar(bar, ep, false);
  }

  gridbar(bar, ep, true);   // FLUSH before epilogue reads of QA/CTX

  // ===== Epilogue: MLP head + argmax (block = one t) =====
  {
    const int t = blk;
    const int sl = wv, b = lane;
    float acc1[32];
    #pragma unroll
    for (int i = 0; i < 32; ++i) acc1[i] = 0.f;
    #pragma unroll 1
    for (int h = 0; h < 2; ++h) {
      __syncthreads();
      const float* src = (h == 0) ? (QA + t * 8192) : (CTX + (t + 1) * 8192);
      #pragma unroll
      for (int i = 0; i < 16; ++i) {
        int idx = tid + i * 512;
        SMf[(idx >> 6) * 65 + (idx & 63)] = src[idx];
      }
      __syncthreads();
      const float* w1 = A.w_mlp1 + (sl * 32) * 256 + h * 128;
      #pragma unroll 2
      for (int k = 0; k < 128; ++k) {
        float xv = SMf[k * 65 + b];
        #pragma unroll
        for (int m2 = 0; m2 < 32; ++m2) acc1[m2] = fmaf(w1[m2 * 256 + k], xv, acc1[m2]);
      }
    }
    #pragma unroll
    for (int m2 = 0; m2 < 32; ++m2) {
      float v2 = acc1[m2] + A.b_mlp1[sl * 32 + m2];
      acc1[m2] = (v2 >= 0.f) ? v2 : 0.9f * v2;          // LeakyReLU(0.9)
    }
    __syncthreads();
    #pragma unroll
    for (int m2 = 0; m2 < 32; ++m2) SMf[(sl * 32 + m2) * 65 + b] = acc1[m2];
    __syncthreads();
    float y[8];
    #pragma unroll
    for (int m2 = 0; m2 < 8; ++m2) y[m2] = 0.f;
    const float* w2 = A.w_mlp2 + (sl * 8) * 256;
    #pragma unroll 2
    for (int k = 0; k < 256; ++k) {
      float xv = SMf[k * 65 + b];
      #pragma unroll
      for (int m2 = 0; m2 < 8; ++m2) y[m2] = fmaf(w2[m2 * 256 + k], xv, y[m2]);
    }
    #pragma unroll
    for (int m2 = 0; m2 < 8; ++m2) y[m2] += A.b_mlp2[sl * 8 + m2];
    *(float4*)(out0 + b * 16384 + t * 64 + sl * 8)     = make_float4(y[0], y[1], y[2], y[3]);
    *(float4*)(out0 + b * 16384 + t * 64 + sl * 8 + 4) = make_float4(y[4], y[5], y[6], y[7]);
    __syncthreads();
    #pragma unroll
    for (int m2 = 0; m2 < 8; ++m2) SMf[(sl * 8 + m2) * 65 + b] = y[m2];
    __syncthreads();
    if (tid < 64) {
      float best = SMf[tid];
      int bi = 0;
      #pragma unroll 1
      for (int v = 1; v < 64; ++v) {
        float val = SMf[v * 65 + tid];
        if (val > best) { best = val; bi = v; }   // first-occurrence argmax
      }
      out1[tid * 256 + t] = (float)bi;
    }
  }
}

extern "C" void kernel_launch(void* const* d_in, const int* in_sizes, int n_in,
                              void* d_out, int out_size, void* d_ws, size_t ws_size,
                              hipStream_t stream) {
  if (ws_size < (size_t)WS_TOTAL * 4) return;   // ~39.8 MB scratch
  KArgs a;
  a.enc_key = (const float*)d_in[0];
  a.value   = (const float*)d_in[1];
  a.labels  = (const int*)d_in[2];
  a.seqlens = (const int*)d_in[3];
  a.sos     = (const int*)d_in[4];
  a.w_emb  = (const float*)d_in[6];  a.b_emb  = (const float*)d_in[7];
  a.w_ih0  = (const float*)d_in[8];  a.w_hh0  = (const float*)d_in[9];
  a.b_ih0  = (const float*)d_in[10]; a.b_hh0  = (const float*)d_in[11];
  a.w_ih1  = (const float*)d_in[12]; a.w_hh1  = (const float*)d_in[13];
  a.b_ih1  = (const float*)d_in[14]; a.b_hh1  = (const float*)d_in[15];
  a.w_ih2  = (const float*)d_in[16]; a.w_hh2  = (const float*)d_in[17];
  a.b_ih2  = (const float*)d_in[18]; a.b_hh2  = (const float*)d_in[19];
  a.w_fc   = (const float*)d_in[20]; a.b_fc   = (const float*)d_in[21];
  a.w_mlp1 = (const float*)d_in[22]; a.b_mlp1 = (const float*)d_in[23];
  a.w_mlp2 = (const float*)d_in[24]; a.b_mlp2 = (const float*)d_in[25];
  a.out = (float*)d_out;
  a.ws  = (float*)d_ws;

  int* bar = (int*)((float*)d_ws + OF_BAR);
  hipLaunchKernelGGL(bar_init_kernel, dim3(1), dim3(512), 0, stream, bar);

  void* args[] = { (void*)&a };
  hipLaunchCooperativeKernel(reinterpret_cast<void*>(dec_kernel),
                             dim3(256), dim3(512), args, 0, stream);
}

// Round 5
// 49644.513 us; speedup vs baseline: 1.0541x; 1.0541x over previous
//
#include <hip/hip_runtime.h>

typedef unsigned int u32;
#define DEVI __device__ __forceinline__

// ---- JAX threefry2x32 (exact) ----
DEVI void tf2x32(u32 k0, u32 k1, u32 x0, u32 x1, u32& o0, u32& o1) {
  u32 ks2 = k0 ^ k1 ^ 0x1BD11BDAu;
  x0 += k0; x1 += k1;
#define TFR(r) { x0 += x1; x1 = (x1 << (r)) | (x1 >> (32 - (r))); x1 ^= x0; }
  TFR(13) TFR(15) TFR(26) TFR(6)
  x0 += k1; x1 += ks2 + 1u;
  TFR(17) TFR(29) TFR(16) TFR(24)
  x0 += ks2; x1 += k0 + 2u;
  TFR(13) TFR(15) TFR(26) TFR(6)
  x0 += k0; x1 += k1 + 3u;
  TFR(17) TFR(29) TFR(16) TFR(24)
  x0 += k1; x1 += ks2 + 4u;
  TFR(13) TFR(15) TFR(26) TFR(6)
  x0 += ks2; x1 += k0 + 5u;
#undef TFR
  o0 = x0; o1 = x1;
}

DEVI float jax_uniform(u32 k0, u32 k1, u32 idx) {
  u32 a, b; tf2x32(k0, k1, 0u, idx, a, b);
  u32 bits = a ^ b;
  return __uint_as_float((bits >> 9) | 0x3F800000u) - 1.0f;
}

DEVI float sigmoidf_(float x) { return 1.0f / (1.0f + expf(-x)); }

// coherent (agent-scope, L2-bypassing) access for cross-block MUTABLE state only
DEVI float AL(const float* p) {
  return __hip_atomic_load((float*)p, __ATOMIC_RELAXED, __HIP_MEMORY_SCOPE_AGENT);
}
DEVI void AS(float* p, float v) {
  __hip_atomic_store(p, v, __ATOMIC_RELAXED, __HIP_MEMORY_SCOPE_AGENT);
}

// async global->LDS, 16B per lane (dest = wave-uniform base + lane*16)
typedef const __attribute__((address_space(1))) u32* gas1;
typedef __attribute__((address_space(3))) u32* las3;
DEVI void gl16(const float* g, float* l) {
  __builtin_amdgcn_global_load_lds((gas1)g, (las3)l, 16, 0, 0);
}
#define WAITV(N) asm volatile("s_waitcnt vmcnt(" #N ")" ::: "memory")

struct KArgs {
  const float* enc_key; const float* value;
  const int* labels; const int* seqlens; const int* sos;
  const float* w_emb; const float* b_emb;
  const float* w_ih0; const float* w_hh0; const float* b_ih0; const float* b_hh0;
  const float* w_ih1; const float* w_hh1; const float* b_ih1; const float* b_hh1;
  const float* w_ih2; const float* w_hh2; const float* b_ih2; const float* b_hh2;
  const float* w_fc; const float* b_fc;
  const float* w_mlp1; const float* b_mlp1;
  const float* w_mlp2; const float* b_mlp2;
  float* out; float* ws;
};

// ws offsets (floats)
#define OF_LS     0
#define OF_Y0     1048576
#define OF_XEMB   1052672
#define OF_HSB    5246976   // [3][2][512][64]
#define OF_CSB    5443584
#define OF_CTX    5640192   // [257][128][64]
#define OF_CTXQ   7745536   // [64][4][128]
#define OF_MSQ    7778304   // [64][4][2]
#define OF_QA     7778816   // [256][128][64]
#define OF_WPK    9875968   // packed LSTM weights
#define OF_WFCT   15905280  // [512][128]
#define OF_BAR    15970816  // 4096 ints
#define OF_QBAR   15974912  // 1024 ints
#define OF_HT     15975936  // [2][64][512] transposed h2
#define WS_TOTAL  16041472
#define WP1 1835008
#define WP2 3932160

// fence-free two-level grid barrier: 16 groups x 16 blocks, monotonic, 16 release lines
DEVI void bar_arrive_wait(int* bar, int& ep) {
  if (threadIdx.x == 0) {
    int g = (int)(blockIdx.x & 15);
    int old = __hip_atomic_fetch_add(bar + g * 64, 1, __ATOMIC_RELAXED, __HIP_MEMORY_SCOPE_AGENT);
    if (old == ep * 16 - 1) {
      int o2 = __hip_atomic_fetch_add(bar + 1024, 1, __ATOMIC_RELAXED, __HIP_MEMORY_SCOPE_AGENT);
      if (o2 == ep * 16 - 1) {
        #pragma unroll
        for (int gg = 0; gg < 16; ++gg)
          __hip_atomic_store(bar + 2048 + gg * 64, ep, __ATOMIC_RELAXED, __HIP_MEMORY_SCOPE_AGENT);
      }
    }
    while (__hip_atomic_load(bar + 2048 + g * 64, __ATOMIC_RELAXED, __HIP_MEMORY_SCOPE_AGENT) < ep)
      __builtin_amdgcn_s_sleep(1);
  }
  __syncthreads();
  ++ep;
}

DEVI void gridbar_fast(int* bar, int& ep) {
  WAITV(0);
  __syncthreads();
  bar_arrive_wait(bar, ep);
}

DEVI void gridbar_flush(int* bar, int& ep) {
  WAITV(0);
  __syncthreads();
  if (threadIdx.x == 0) __threadfence();   // release: wb L2
  __syncthreads();
  bar_arrive_wait(bar, ep);
  if (threadIdx.x == 0) __threadfence();   // acquire: inv L1/L2
  __syncthreads();
}

__global__ void bar_init_kernel(int* bar) {
  for (int i = 0; i < 5; ++i) {
    int idx = threadIdx.x + i * 1024;
    if (idx < 5120) bar[idx] = 0;
  }
}

// B=64 TK=2048 TL=256 V=64 E=256 KV=128 H=512 MH=256
__global__ __launch_bounds__(1024, 4) void dec_kernel(KArgs A) {
  const int blk = blockIdx.x;
  const int tid = threadIdx.x;
  const int lane = tid & 63;
  const int w = tid >> 6;

  float* const LS   = A.ws + OF_LS;
  float* const Y0   = A.ws + OF_Y0;
  float* const XEMB = A.ws + OF_XEMB;
  float* const HSb  = A.ws + OF_HSB;
  float* const CSb  = A.ws + OF_CSB;
  float* const CTX  = A.ws + OF_CTX;
  float* const CTXQ = A.ws + OF_CTXQ;
  float* const MSQ  = A.ws + OF_MSQ;
  float* const QA   = A.ws + OF_QA;
  float* const WPACK= A.ws + OF_WPK;
  float* const WFCT = A.ws + OF_WFCT;
  float* const HT   = A.ws + OF_HT;
  int*   const bar  = (int*)(A.ws + OF_BAR);
  int*   const qbar = (int*)(A.ws + OF_QBAR);

  float* const out0 = A.out;              // y_hat [64][256][64]
  float* const out1 = A.out + 1048576;    // argmax as float [64][256]
  float* const out2 = A.out + 1064960;    // labels.T [64][256]
  float* const out3 = A.out + 1081344;    // labels_smoothed [64][256][64]
  float* const out4 = A.out + 2129920;    // attentions [64][2048][256]

  __shared__ __align__(16) float SMf[39424];   // 154 KB
  int ep = 1;

  const int bq = blk >> 2, ch = blk & 3;

  u32 KA0, KA1, KB0, KB1;
  tf2x32(0u, 42u, 0u, 0u, KA0, KA1);
  tf2x32(0u, 42u, 0u, 1u, KB0, KB1);

  // ===== Prologue: pack weights (all blocks), then role work =====
  {
    for (int f = tid; f < 7168; f += 1024) {
      int r = f / 896, off = f - r * 896;
      int row = (r >> 1) * 512 + blk * 2 + (r & 1);
      float v = (off < 384) ? A.w_ih0[row * 384 + off] : A.w_hh0[row * 512 + off - 384];
      WPACK[blk * 7168 + f] = v;
    }
    for (int f = tid; f < 8192; f += 1024) {
      int r = f >> 10, off = f & 1023;
      int row = (r >> 1) * 512 + blk * 2 + (r & 1);
      WPACK[WP1 + blk * 8192 + f] = (off < 512) ? A.w_ih1[row * 512 + off] : A.w_hh1[row * 512 + off - 512];
    }
    for (int f = tid; f < 8192; f += 1024) {
      int r = f >> 10, off = f & 1023;
      int row = (r >> 1) * 512 + blk * 2 + (r & 1);
      WPACK[WP2 + blk * 8192 + f] = (off < 512) ? A.w_ih2[row * 512 + off] : A.w_hh2[row * 512 + off - 512];
    }
  }
  if (blk < 65) {
    int slot = blk * 1024 + tid;
    int r = slot >> 2, q = slot & 3;
    if (r < 16448) {
      bool isY0 = (r >= 16384);
      int t = 0, b, label;
      u32 key0, key1, base;
      if (!isY0) {
        t = r >> 6; b = r & 63;
        label = A.labels[t * 64 + b];
        key0 = KA0; key1 = KA1; base = (u32)(r * 64);
      } else {
        b = r - 16384;
        label = A.sos[0];
        key0 = KB0; key1 = KB1; base = (u32)(b * 64);
      }
      float sv[16];
      float mx = -3.0e38f;
      #pragma unroll
      for (int j = 0; j < 16; ++j) {
        int v = (q << 4) + j;
        float u = jax_uniform(key0, key1, base + (u32)v);
        float inner = -logf(u + 1e-10f) + 1e-10f;
        float noise = -logf(inner);
        float s = noise + ((v == label) ? 1.0f : 0.0f);
        sv[j] = s; mx = fmaxf(mx, s);
      }
      mx = fmaxf(mx, __shfl_xor(mx, 1));
      mx = fmaxf(mx, __shfl_xor(mx, 2));
      float sum = 0.f;
      #pragma unroll
      for (int j = 0; j < 16; ++j) { sv[j] = expf(sv[j] - mx); sum += sv[j]; }
      sum += __shfl_xor(sum, 1);
      sum += __shfl_xor(sum, 2);
      float inv = 1.0f / sum;
      if (!isY0) {
        #pragma unroll
        for (int j = 0; j < 16; ++j) {
          int v = (q << 4) + j;
          float val = sv[j] * inv;
          LS[r * 64 + v] = val;
          out3[b * 16384 + t * 64 + v] = val;
        }
        if (q == 0) out2[b * 256 + t] = (float)label;
      } else {
        #pragma unroll
        for (int j = 0; j < 16; ++j) Y0[b * 64 + (q << 4) + j] = sv[j] * inv;
      }
    }
  } else if (blk < 128) {
    // zero h/c + CTX[0] (contiguous 401408 at HSb) + build WFCT (65536)
    const int total1 = 401408, total2 = 401408 + 65536;
    for (int idx = (blk - 65) * 1024 + tid; idx < total2; idx += 63 * 1024) {
      if (idx < total1) HSb[idx] = 0.f;
      else {
        int i2 = idx - total1;
        int kv = i2 >> 9, j = i2 & 511;
        WFCT[j * 128 + kv] = A.w_fc[kv * 512 + j];
      }
    }
  }
  gridbar_flush(bar, ep);    // publish prologue writes

  // ===== P1: embeddings XEMB[t][e][b] =====
  {
    const int t = blk;
    const float* src = (t == 0) ? Y0 : (LS + (t - 1) * 4096);
    #pragma unroll
    for (int i = 0; i < 4; ++i) {
      int idx = tid + i * 1024;
      SMf[(idx >> 6) * 65 + (idx & 63)] = src[idx];
    }
    __syncthreads();
    const int sl = w, b = lane;
    float* dst = XEMB + t * 16384;
    #pragma unroll 1
    for (int e0 = 0; e0 < 16; ++e0) {
      int e = sl * 16 + e0;
      const float* we = A.w_emb + e * 64;
      float acc = A.b_emb[e];
      #pragma unroll 8
      for (int v = 0; v < 64; ++v) acc = fmaf(we[v], SMf[b * 65 + v], acc);
      dst[e * 64 + b] = acc;
    }
  }
  gridbar_flush(bar, ep);    // publish XEMB

  const int lenb = A.seqlens[bq];

// K/V staging macros (tile = 128 t' x 128 k = 64KB, 4 gl16/wave)
#define KSTAGE(TILE, BUFI) { \
  const float* kg = A.enc_key + (size_t)bq * 262144 + (size_t)(ch * 512 + (TILE) * 128) * 128; \
  float* dst_ = SMf + (BUFI) * 16384; \
  _Pragma("unroll") for (int s_ = 0; s_ < 4; ++s_) { \
    int i2_ = w * 4 + s_; int rr_ = 2 * i2_ + (lane >> 5); \
    gl16(kg + rr_ * 128 + (((lane & 31) ^ (rr_ & 7)) << 2), dst_ + i2_ * 256); } }
#define VSTAGE(TILE, BUFI) { \
  const float* vg = A.value + (size_t)bq * 262144 + (size_t)(ch * 512 + (TILE) * 128) * 128; \
  float* dst_ = SMf + (BUFI) * 16384; \
  _Pragma("unroll") for (int s_ = 0; s_ < 4; ++s_) { \
    int i2_ = w * 4 + s_; \
    gl16(vg + i2_ * 256 + lane * 4, dst_ + i2_ * 256); } }

  // ===== main recurrence: 4 fence-free barriers/step =====
  #pragma unroll 1
  for (int t = 0; t < 256; ++t) {
    const int p = t & 1;

    // ---- 3 LSTM layer phases ----
    #pragma unroll 1
    for (int l = 0; l < 3; ++l) {
      const int b = lane;
      const int j0 = blk * 2;
      float* WL  = SMf;             // weights [8][KL]
      float* RED = SMf + 16384;     // 8192 reduction

      const float* wp = (l == 0) ? (WPACK + blk * 7168)
                      : (l == 1) ? (WPACK + WP1 + blk * 8192)
                                 : (WPACK + WP2 + blk * 8192);
      const int NW = (l == 0) ? 28 : 32;
      for (int i = w; i < NW; i += 16) gl16(wp + i * 256 + lane * 4, WL + i * 256);
      WAITV(0);
      __syncthreads();

      float acc[8] = {0.f,0.f,0.f,0.f,0.f,0.f,0.f,0.f};
      if (l == 0) {
        const float* xe = XEMB + t * 16384 + b;
        const float* ct = CTX + t * 8192 + b;
        const float* h0 = HSb + p * 32768 + b;
        const int kb = w * 56;
        #pragma unroll 4
        for (int q4 = 0; q4 < 14; ++q4) {
          int k0 = kb + q4 * 4;
          float xv[4];
          #pragma unroll
          for (int j = 0; j < 4; ++j) {
            int k = k0 + j;
            xv[j] = (k < 256) ? xe[k * 64]
                  : (k < 384) ? AL(ct + (k - 256) * 64)
                              : AL(h0 + (k - 384) * 64);
          }
          #pragma unroll
          for (int r = 0; r < 8; ++r) {
            float4 w4 = *(const float4*)&WL[r * 896 + k0];
            acc[r] = fmaf(w4.w, xv[3], fmaf(w4.z, xv[2], fmaf(w4.y, xv[1], fmaf(w4.x, xv[0], acc[r]))));
          }
        }
      } else {
        const float* hin = HSb + ((l - 1) * 2 + (p ^ 1)) * 32768 + b;
        const float* hpr = HSb + (l * 2 + p) * 32768 + b;
        const int kb = w * 64;
        #pragma unroll 4
        for (int q4 = 0; q4 < 16; ++q4) {
          int k0 = kb + q4 * 4;
          float xv[4];
          #pragma unroll
          for (int j = 0; j < 4; ++j) {
            int k = k0 + j;
            xv[j] = (k < 512) ? AL(hin + k * 64) : AL(hpr + (k - 512) * 64);
          }
          #pragma unroll
          for (int r = 0; r < 8; ++r) {
            float4 w4 = *(const float4*)&WL[r * 1024 + k0];
            acc[r] = fmaf(w4.w, xv[3], fmaf(w4.z, xv[2], fmaf(w4.y, xv[1], fmaf(w4.x, xv[0], acc[r]))));
          }
        }
      }
      #pragma unroll
      for (int r = 0; r < 8; ++r) RED[w * 512 + r * 64 + b] = acc[r];
      __syncthreads();
      if (tid < 128) {
        const float *bih, *bhh;
        if (l == 0)      { bih = A.b_ih0; bhh = A.b_hh0; }
        else if (l == 1) { bih = A.b_ih1; bhh = A.b_hh1; }
        else             { bih = A.b_ih2; bhh = A.b_hh2; }
        int jj = tid >> 6, bb = tid & 63;
        int j = j0 + jj;
        float g4[4];
        #pragma unroll
        for (int g = 0; g < 4; ++g) {
          float s = 0.f;
          #pragma unroll
          for (int w2 = 0; w2 < 16; ++w2) s += RED[w2 * 512 + (g * 2 + jj) * 64 + bb];
          int row = g * 512 + j;
          g4[g] = s + bih[row] + bhh[row];
        }
        float cprev = AL(CSb + (l * 2 + p) * 32768 + j * 64 + bb);
        float c2 = sigmoidf_(g4[1]) * cprev + sigmoidf_(g4[0]) * tanhf(g4[2]);
        float h2 = sigmoidf_(g4[3]) * tanhf(c2);
        AS(CSb + (l * 2 + (p ^ 1)) * 32768 + j * 64 + bb, c2);
        AS(HSb + (l * 2 + (p ^ 1)) * 32768 + j * 64 + bb, h2);
        if (l == 2) AS(HT + (p ^ 1) * 32768 + bb * 512 + j, h2);
      }
      __syncthreads();
      if (l == 2) {
        // pre-issue K tiles 0,1 so they fly during the barrier wait
        KSTAGE(0, 0);
        KSTAGE(1, 1);
        WAITV(8);           // drains all AS stores (in-order), K loads stay in flight
        __syncthreads();
        bar_arrive_wait(bar, ep);
      } else {
        gridbar_fast(bar, ep);
      }
    }

    // ---- ATTN phase: block=(bq,ch); K/V double-buffered 64KB tiles ----
    {
      float* H2C = SMf + 32768;   // 512
      float* QP  = SMf + 33280;   // 1024 (also energy partials)
      float* QV  = SMf + 34304;   // 128
      float* ZS  = SMf + 34432;   // 512
      float* MR  = SMf + 34944;   // 32
      float* PR  = SMf + 34976;   // 4096

      // h2 (coalesced via transposed HT) -> LDS
      if (tid < 512) H2C[tid] = AL(HT + (p ^ 1) * 32768 + bq * 512 + tid);
      __syncthreads();
      // q = WFCT^T h2 + b_fc  (8 j-groups of 64)
      {
        int kv = tid & 127, jg = tid >> 7;
        const float* wf = WFCT + (jg * 64) * 128 + kv;
        float pa = 0.f;
        #pragma unroll 8
        for (int jl = 0; jl < 64; ++jl) pa = fmaf(wf[jl * 128], H2C[jg * 64 + jl], pa);
        QP[jg * 128 + kv] = pa;
      }
      __syncthreads();
      if (tid < 128) {
        float qv = A.b_fc[tid];
        #pragma unroll
        for (int g = 0; g < 8; ++g) qv += QP[g * 128 + tid];
        QV[tid] = qv;
        if (ch == 0) QA[t * 8192 + tid * 64 + bq] = qv;
      }
      __syncthreads();

      // energy over 4 K tiles (double buffer), swizzled reads
      #pragma unroll 1
      for (int tu = 0; tu < 4; ++tu) {
        WAITV(4);
        __syncthreads();
        {
          int tl = tid & 127, kq = tid >> 7, rot = tl & 7;
          const float* KB = SMf + (tu & 1) * 16384 + tl * 128;
          float e = 0.f;
          #pragma unroll
          for (int gi = 0; gi < 4; ++gi) {
            int g = kq * 4 + gi, slot = g ^ rot;
            float4 k4 = *(const float4*)&KB[slot * 4];
            float4 q4 = *(const float4*)&QV[g * 4];
            e += k4.x * q4.x + k4.y * q4.y + k4.z * q4.z + k4.w * q4.w;
          }
          QP[kq * 128 + tl] = e;
        }
        __syncthreads();
        if (tu == 0)      { KSTAGE(2, 0); }
        else if (tu == 1) { KSTAGE(3, 1); }
        else if (tu == 2) { VSTAGE(0, 0); }
        else              { VSTAGE(1, 1); }
        if (tid < 128) {
          float ee = 0.f;
          #pragma unroll
          for (int g = 0; g < 8; ++g) ee += QP[g * 128 + tid];
          int ta = ch * 512 + tu * 128 + tid;
          ZS[tu * 128 + tid] = (ta < lenb) ? ee : 0.0f;   // energy * mask
        }
      }
      // chunk softmax over 512
      __syncthreads();
      float z = (tid < 512) ? ZS[tid] : -3.0e38f;
      float mm = z;
      #pragma unroll
      for (int d = 1; d < 64; d <<= 1) mm = fmaxf(mm, __shfl_xor(mm, d));
      if (lane == 0 && w < 8) MR[w] = mm;
      __syncthreads();
      mm = MR[0];
      #pragma unroll
      for (int i2 = 1; i2 < 8; ++i2) mm = fmaxf(mm, MR[i2]);
      float ex = 0.f;
      if (tid < 512) { ex = expf(z - mm); ZS[tid] = ex; }
      float ss = ex;
      #pragma unroll
      for (int d = 1; d < 64; d <<= 1) ss += __shfl_xor(ss, d);
      if (lane == 0 && w < 8) MR[8 + w] = ss;
      __syncthreads();
      float S = 0.f;
      #pragma unroll
      for (int i2 = 0; i2 < 8; ++i2) S += MR[8 + i2];
      const float m_ch = mm;
      if (tid == 0) {
        AS(MSQ + bq * 8 + ch * 2, m_ch);
        AS(MSQ + bq * 8 + ch * 2 + 1, S);
      }
      // PV over 4 V tiles
      float c0 = 0.f, c1 = 0.f, c2 = 0.f, c3 = 0.f;
      const int tg = tid >> 5, kv4 = (tid & 31) * 4;
      #pragma unroll 1
      for (int vt = 0; vt < 4; ++vt) {
        if (vt < 3) { WAITV(4); } else { WAITV(0); }
        __syncthreads();
        const float* B = SMf + (vt & 1) * 16384;
        #pragma unroll
        for (int i2 = 0; i2 < 4; ++i2) {
          int r = tg * 4 + i2;
          float a = ZS[vt * 128 + r];
          float4 v4 = *(const float4*)&B[r * 128 + kv4];
          c0 = fmaf(a, v4.x, c0); c1 = fmaf(a, v4.y, c1);
          c2 = fmaf(a, v4.z, c2); c3 = fmaf(a, v4.w, c3);
        }
        __syncthreads();
        if (vt == 0)      { VSTAGE(2, 0); }
        else if (vt == 1) { VSTAGE(3, 1); }
      }
      PR[tg * 128 + kv4]     = c0;
      PR[tg * 128 + kv4 + 1] = c1;
      PR[tg * 128 + kv4 + 2] = c2;
      PR[tg * 128 + kv4 + 3] = c3;
      __syncthreads();
      float ownpart = 0.f;
      if (tid < 128) {
        float s = 0.f;
        #pragma unroll
        for (int g2 = 0; g2 < 32; ++g2) s += PR[g2 * 128 + tid];
        ownpart = s;
        AS(CTXQ + bq * 512 + ch * 128 + tid, s);
      }
      WAITV(0);
      __syncthreads();
      // quad-team micro-barrier (4 chunk-blocks of this batch)
      if (tid == 0) {
        int* qc = qbar + bq * 16;
        __hip_atomic_fetch_add(qc, 1, __ATOMIC_RELAXED, __HIP_MEMORY_SCOPE_AGENT);
        int tgt = (t + 1) * 4;
        while (__hip_atomic_load(qc, __ATOMIC_RELAXED, __HIP_MEMORY_SCOPE_AGENT) < tgt)
          __builtin_amdgcn_s_sleep(1);
      }
      __syncthreads();
      if (tid < 8) MR[16 + tid] = AL(MSQ + bq * 8 + tid);
      __syncthreads();
      float mall = fmaxf(fmaxf(MR[16], MR[18]), fmaxf(MR[20], MR[22]));
      float Z = MR[17] * expf(MR[16] - mall) + MR[19] * expf(MR[18] - mall)
              + MR[21] * expf(MR[20] - mall) + MR[23] * expf(MR[22] - mall);
      float invZ = 1.0f / Z;
      if (tid < 512)
        out4[(size_t)bq * 524288 + (size_t)(ch * 512 + tid) * 256 + t]
            = ZS[tid] * (expf(m_ch - mall) * invZ);
      if (ch == 0 && tid < 128) {
        float f0 = expf(MR[16] - mall) * invZ;
        float f1 = expf(MR[18] - mall) * invZ;
        float f2 = expf(MR[20] - mall) * invZ;
        float f3 = expf(MR[22] - mall) * invZ;
        float cx = ownpart * f0
                 + AL(CTXQ + bq * 512 + 128 + tid) * f1
                 + AL(CTXQ + bq * 512 + 256 + tid) * f2
                 + AL(CTXQ + bq * 512 + 384 + tid) * f3;
        AS(CTX + (t + 1) * 8192 + tid * 64 + bq, cx);
      }
    }
    gridbar_fast(bar, ep);
  }

  gridbar_flush(bar, ep);   // publish QA (plain) before epilogue reads

  // ===== Epilogue: MLP head + argmax (block = one t) =====
  {
    const int t = blk;
    const int sl = w, b = lane;
    const float* qa_t = QA + t * 8192;
    const float* ct1 = CTX + (t + 1) * 8192;
    #pragma unroll
    for (int i = 0; i < 8; ++i) {
      int idx = tid + i * 1024;
      SMf[(idx >> 6) * 65 + (idx & 63)] = qa_t[idx];
      SMf[(128 + (idx >> 6)) * 65 + (idx & 63)] = ct1[idx];
    }
    __syncthreads();
    float a1[16];
    #pragma unroll
    for (int i = 0; i < 16; ++i) a1[i] = 0.f;
    const float* w1 = A.w_mlp1 + (sl * 16) * 256;
    #pragma unroll 2
    for (int k = 0; k < 256; ++k) {
      float xv = SMf[k * 65 + b];
      #pragma unroll
      for (int m2 = 0; m2 < 16; ++m2) a1[m2] = fmaf(w1[m2 * 256 + k], xv, a1[m2]);
    }
    float* ACT = SMf + 16640;
    #pragma unroll
    for (int m2 = 0; m2 < 16; ++m2) {
      float v2 = a1[m2] + A.b_mlp1[sl * 16 + m2];
      ACT[(sl * 16 + m2) * 65 + b] = (v2 >= 0.f) ? v2 : 0.9f * v2;   // LeakyReLU(0.9)
    }
    __syncthreads();
    float y[4] = {0.f, 0.f, 0.f, 0.f};
    const float* w2 = A.w_mlp2 + (sl * 4) * 256;
    #pragma unroll 2
    for (int k = 0; k < 256; ++k) {
      float xv = ACT[k * 65 + b];
      #pragma unroll
      for (int m2 = 0; m2 < 4; ++m2) y[m2] = fmaf(w2[m2 * 256 + k], xv, y[m2]);
    }
    #pragma unroll
    for (int m2 = 0; m2 < 4; ++m2) y[m2] += A.b_mlp2[sl * 4 + m2];
    *(float4*)(out0 + b * 16384 + t * 64 + sl * 4) = make_float4(y[0], y[1], y[2], y[3]);
    float* YB = SMf + 33280;
    #pragma unroll
    for (int m2 = 0; m2 < 4; ++m2) YB[(sl * 4 + m2) * 65 + b] = y[m2];
    __syncthreads();
    if (tid < 64) {
      float best = YB[tid];
      int bi = 0;
      #pragma unroll 1
      for (int v = 1; v < 64; ++v) {
        float val = YB[v * 65 + tid];
        if (val > best) { best = val; bi = v; }   // first-occurrence argmax
      }
      out1[tid * 256 + t] = (float)bi;
    }
  }
}

extern "C" void kernel_launch(void* const* d_in, const int* in_sizes, int n_in,
                              void* d_out, int out_size, void* d_ws, size_t ws_size,
                              hipStream_t stream) {
  if (ws_size < (size_t)WS_TOTAL * 4) return;   // ~64 MB scratch
  KArgs a;
  a.enc_key = (const float*)d_in[0];
  a.value   = (const float*)d_in[1];
  a.labels  = (const int*)d_in[2];
  a.seqlens = (const int*)d_in[3];
  a.sos     = (const int*)d_in[4];
  a.w_emb  = (const float*)d_in[6];  a.b_emb  = (const float*)d_in[7];
  a.w_ih0  = (const float*)d_in[8];  a.w_hh0  = (const float*)d_in[9];
  a.b_ih0  = (const float*)d_in[10]; a.b_hh0  = (const float*)d_in[11];
  a.w_ih1  = (const float*)d_in[12]; a.w_hh1  = (const float*)d_in[13];
  a.b_ih1  = (const float*)d_in[14]; a.b_hh1  = (const float*)d_in[15];
  a.w_ih2  = (const float*)d_in[16]; a.w_hh2  = (const float*)d_in[17];
  a.b_ih2  = (const float*)d_in[18]; a.b_hh2  = (const float*)d_in[19];
  a.w_fc   = (const float*)d_in[20]; a.b_fc   = (const float*)d_in[21];
  a.w_mlp1 = (const float*)d_in[22]; a.b_mlp1 = (const float*)d_in[23];
  a.w_mlp2 = (const float*)d_in[24]; a.b_mlp2 = (const float*)d_in[25];
  a.out = (float*)d_out;
  a.ws  = (float*)d_ws;

  int* bar = (int*)((float*)d_ws + OF_BAR);
  hipLaunchKernelGGL(bar_init_kernel, dim3(1), dim3(1024), 0, stream, bar);

  void* args[] = { (void*)&a };
  hipLaunchCooperativeKernel(reinterpret_cast<void*>(dec_kernel),
                             dim3(256), dim3(1024), args, 0, stream);
}

// Round 9
// 28760.916 us; speedup vs baseline: 1.8194x; 1.7261x over previous
//
#include <hip/hip_runtime.h>

typedef unsigned int u32;
typedef float nf4 __attribute__((ext_vector_type(4)));
#define DEVI __device__ __forceinline__

// ---- JAX threefry2x32 (exact) ----
DEVI void tf2x32(u32 k0, u32 k1, u32 x0, u32 x1, u32& o0, u32& o1) {
  u32 ks2 = k0 ^ k1 ^ 0x1BD11BDAu;
  x0 += k0; x1 += k1;
#define TFR(r) { x0 += x1; x1 = (x1 << (r)) | (x1 >> (32 - (r))); x1 ^= x0; }
  TFR(13) TFR(15) TFR(26) TFR(6)
  x0 += k1; x1 += ks2 + 1u;
  TFR(17) TFR(29) TFR(16) TFR(24)
  x0 += ks2; x1 += k0 + 2u;
  TFR(13) TFR(15) TFR(26) TFR(6)
  x0 += k0; x1 += k1 + 3u;
  TFR(17) TFR(29) TFR(16) TFR(24)
  x0 += k1; x1 += ks2 + 4u;
  TFR(13) TFR(15) TFR(26) TFR(6)
  x0 += ks2; x1 += k0 + 5u;
#undef TFR
  o0 = x0; o1 = x1;
}

DEVI float jax_uniform(u32 k0, u32 k1, u32 idx) {
  u32 a, b; tf2x32(k0, k1, 0u, idx, a, b);
  u32 bits = a ^ b;
  return __uint_as_float((bits >> 9) | 0x3F800000u) - 1.0f;
}

DEVI float sigmoidf_(float x) { return 1.0f / (1.0f + expf(-x)); }

// ---- validated coherence primitives (R3/R4-proven) ----
DEVI float AL(const float* p) {
  return __hip_atomic_load((float*)p, __ATOMIC_RELAXED, __HIP_MEMORY_SCOPE_AGENT);
}
DEVI void AS(float* p, float v) {
  __hip_atomic_store(p, v, __ATOMIC_RELAXED, __HIP_MEMORY_SCOPE_AGENT);
}

// async global->LDS (IMMUTABLE data only), plain cached
typedef const __attribute__((address_space(1))) u32* gas1;
typedef __attribute__((address_space(3))) u32* las3;
DEVI void gl16n(const float* g, float* l) { __builtin_amdgcn_global_load_lds((gas1)g, (las3)l, 16, 0, 0); }
#define WAITV(N) asm volatile("s_waitcnt vmcnt(" #N ")" ::: "memory")
#define SBAR __builtin_amdgcn_sched_barrier(0)

struct KArgs {
  const float* enc_key; const float* value;
  const int* labels; const int* seqlens; const int* sos;
  const float* w_emb; const float* b_emb;
  const float* w_ih0; const float* w_hh0; const float* b_ih0; const float* b_hh0;
  const float* w_ih1; const float* w_hh1; const float* b_ih1; const float* b_hh1;
  const float* w_ih2; const float* w_hh2; const float* b_ih2; const float* b_hh2;
  const float* w_fc; const float* b_fc;
  const float* w_mlp1; const float* b_mlp1;
  const float* w_mlp2; const float* b_mlp2;
  float* out; float* ws;
};

// ws offsets (floats)
#define OF_Y0     0         // 4096
#define OF_XEMB   4096      // 256*16384
#define OF_HSB    4198400   // [3][2][512][64]
#define OF_CSB    4395008
#define OF_CTX    4591616   // [257][128][64]
#define OF_CTXQ   6696960   // [64][4][128]
#define OF_MSQ    6729728   // [64][4][2]
#define OF_QA     6730240   // [256][128][64]
#define OF_WPK    8827392   // packed swizzled LSTM weights per rg
#define OF_WFCT   14856704  // [512][128]
#define OF_BC     14922240  // [3][2048]
#define OF_HT     14928384  // [2][64][512]
#define OF_BAR    14993920  // 4096 ints
#define OF_QBAR   14998016  // 1024 ints
#define OF_ATT    14999040  // [256][64][512]
#define WS_TOTAL  23387648
#define WP1 1835008
#define WP2 3932160

// fence-free two-level grid barrier (R3/R4-proven)
DEVI void bar_arrive_wait(int* bar, int& ep) {
  if (threadIdx.x == 0) {
    int g = (int)(blockIdx.x & 15);
    int old = __hip_atomic_fetch_add(bar + g * 64, 1, __ATOMIC_RELAXED, __HIP_MEMORY_SCOPE_AGENT);
    if (old == ep * 16 - 1) {
      int o2 = __hip_atomic_fetch_add(bar + 1024, 1, __ATOMIC_RELAXED, __HIP_MEMORY_SCOPE_AGENT);
      if (o2 == ep * 16 - 1) {
        #pragma unroll
        for (int gg = 0; gg < 16; ++gg)
          __hip_atomic_store(bar + 2048 + gg * 64, ep, __ATOMIC_RELAXED, __HIP_MEMORY_SCOPE_AGENT);
      }
    }
    while (__hip_atomic_load(bar + 2048 + g * 64, __ATOMIC_RELAXED, __HIP_MEMORY_SCOPE_AGENT) < ep)
      __builtin_amdgcn_s_sleep(1);
  }
  __syncthreads();
  ++ep;
}
DEVI void gridbar_fast(int* bar, int& ep) {
  WAITV(0);
  __syncthreads();
  bar_arrive_wait(bar, ep);
}
DEVI void gridbar_flush(int* bar, int& ep) {
  WAITV(0);
  __syncthreads();
  if (threadIdx.x == 0) __threadfence();
  __syncthreads();
  bar_arrive_wait(bar, ep);
  if (threadIdx.x == 0) __threadfence();
  __syncthreads();
}

__global__ void bar_init_kernel(int* bar) {
  for (int i = 0; i < 5; ++i) {
    int idx = threadIdx.x + i * 1024;
    if (idx < 5120) bar[idx] = 0;
  }
}

// B=64 TK=2048 TL=256 V=64 E=256 KV=128 H=512 MH=256
__global__ __launch_bounds__(1024, 1) void dec_kernel(KArgs A) {
  const int blk = blockIdx.x;
  const int tid = threadIdx.x;
  const int lane = tid & 63;
  const int w = tid >> 6;

  float* const Y0   = A.ws + OF_Y0;
  float* const XEMB = A.ws + OF_XEMB;
  float* const HSb  = A.ws + OF_HSB;
  float* const CSb  = A.ws + OF_CSB;
  float* const CTX  = A.ws + OF_CTX;
  float* const CTXQ = A.ws + OF_CTXQ;
  float* const MSQ  = A.ws + OF_MSQ;
  float* const QA   = A.ws + OF_QA;
  float* const WPACK= A.ws + OF_WPK;
  float* const WFCT = A.ws + OF_WFCT;
  float* const BC   = A.ws + OF_BC;
  float* const HT   = A.ws + OF_HT;
  int*   const bar  = (int*)(A.ws + OF_BAR);
  int*   const qbar = (int*)(A.ws + OF_QBAR);
  float* const ATTS = A.ws + OF_ATT + (size_t)blk * 32768;

  float* const out0 = A.out;
  float* const out1 = A.out + 1048576;
  float* const out2 = A.out + 1064960;
  float* const out3 = A.out + 1081344;
  float* const out4 = A.out + 2129920;

  __shared__ __align__(16) float SMf[39072];   // 156.3 KB
  int ep = 1, eA = 1;

  const int rg = blk >> 2, bg = blk & 3;   // LSTM: row-group x batch-quarter
  const int bq = rg, ch = bg;              // ATTN: batch x chunk

  u32 KA0, KA1, KB0, KB1;
  tf2x32(0u, 42u, 0u, 0u, KA0, KA1);
  tf2x32(0u, 42u, 0u, 1u, KB0, KB1);

  // ===== Prologue =====
  // pack LSTM weights (bg==0 blocks), swizzled [tile][k][pr ^ ((k&7)<<2)]
  if (bg == 0) {
    for (int idx = tid; idx < 28672; idx += 1024) {         // l0: 7 tiles
      int tile = idx >> 12, rem = idx & 4095;
      int k = rem >> 5, slot = rem & 31;
      int pr = slot ^ ((k & 7) << 2);
      int g = pr >> 3, jj = pr & 7;
      int R = g * 512 + rg * 8 + jj;
      int gk = tile * 128 + k;
      WPACK[rg * 28672 + idx] = (gk < 384) ? A.w_ih0[R * 384 + gk] : A.w_hh0[R * 512 + gk - 384];
    }
    for (int idx = tid; idx < 32768; idx += 1024) {         // l1: 8 tiles
      int tile = idx >> 12, rem = idx & 4095;
      int k = rem >> 5, slot = rem & 31;
      int pr = slot ^ ((k & 7) << 2);
      int g = pr >> 3, jj = pr & 7;
      int R = g * 512 + rg * 8 + jj;
      int gk = tile * 128 + k;
      WPACK[WP1 + rg * 32768 + idx] = (gk < 512) ? A.w_ih1[R * 512 + gk] : A.w_hh1[R * 512 + gk - 512];
    }
    for (int idx = tid; idx < 32768; idx += 1024) {         // l2
      int tile = idx >> 12, rem = idx & 4095;
      int k = rem >> 5, slot = rem & 31;
      int pr = slot ^ ((k & 7) << 2);
      int g = pr >> 3, jj = pr & 7;
      int R = g * 512 + rg * 8 + jj;
      int gk = tile * 128 + k;
      WPACK[WP2 + rg * 32768 + idx] = (gk < 512) ? A.w_ih2[R * 512 + gk] : A.w_hh2[R * 512 + gk - 512];
    }
  }
  if (blk < 65) {
    int slot = blk * 1024 + tid;
    int r = slot >> 2, q = slot & 3;
    if (r < 16448) {
      bool isY0 = (r >= 16384);
      int t = 0, b, label;
      u32 key0, key1, base;
      if (!isY0) {
        t = r >> 6; b = r & 63;
        label = A.labels[t * 64 + b];
        key0 = KA0; key1 = KA1; base = (u32)(r * 64);
      } else {
        b = r - 16384;
        label = A.sos[0];
        key0 = KB0; key1 = KB1; base = (u32)(b * 64);
      }
      float sv[16];
      float mx = -3.0e38f;
      #pragma unroll
      for (int j = 0; j < 16; ++j) {
        int v = (q << 4) + j;
        float u = jax_uniform(key0, key1, base + (u32)v);
        float inner = -logf(u + 1e-10f) + 1e-10f;
        float noise = -logf(inner);
        float s = noise + ((v == label) ? 1.0f : 0.0f);
        sv[j] = s; mx = fmaxf(mx, s);
      }
      mx = fmaxf(mx, __shfl_xor(mx, 1));
      mx = fmaxf(mx, __shfl_xor(mx, 2));
      float sum = 0.f;
      #pragma unroll
      for (int j = 0; j < 16; ++j) { sv[j] = expf(sv[j] - mx); sum += sv[j]; }
      sum += __shfl_xor(sum, 1);
      sum += __shfl_xor(sum, 2);
      float inv = 1.0f / sum;
      if (!isY0) {
        #pragma unroll
        for (int j = 0; j < 16; ++j) {
          int v = (q << 4) + j;
          out3[b * 16384 + t * 64 + v] = sv[j] * inv;
        }
        if (q == 0) out2[b * 256 + t] = (float)label;
      } else {
        #pragma unroll
        for (int j = 0; j < 16; ++j) Y0[b * 64 + (q << 4) + j] = sv[j] * inv;
      }
    }
  } else if (blk < 128) {
    const int total1 = 401408, total2 = 401408 + 65536;   // zero h/c/ctx0 + WFCT
    for (int idx = (blk - 65) * 1024 + tid; idx < total2; idx += 63 * 1024) {
      if (idx < total1) HSb[idx] = 0.f;
      else {
        int i2 = idx - total1;
        int kv = i2 >> 9, j = i2 & 511;
        WFCT[j * 128 + kv] = A.w_fc[kv * 512 + j];
      }
    }
  } else if (blk == 255) {
    for (int idx = tid; idx < 6144; idx += 1024) {
      int l = idx >> 11, r = idx & 2047;
      const float* bi = (l == 0) ? A.b_ih0 : (l == 1) ? A.b_ih1 : A.b_ih2;
      const float* bh = (l == 0) ? A.b_hh0 : (l == 1) ? A.b_hh1 : A.b_hh2;
      BC[idx] = bi[r] + bh[r];
    }
  }
  gridbar_flush(bar, ep);

  // ===== P1: embeddings XEMB[t][e][b] (src = out3 / Y0) =====
  {
    const int t = blk;
    #pragma unroll
    for (int i = 0; i < 4; ++i) {
      int idx = tid + i * 1024;
      int b = idx >> 6, v = idx & 63;
      float sval = (t == 0) ? Y0[idx] : out3[b * 16384 + (t - 1) * 64 + v];
      SMf[b * 65 + v] = sval;
    }
    __syncthreads();
    const int b = lane;
    float* dst = XEMB + t * 16384;
    #pragma unroll 1
    for (int e0 = 0; e0 < 16; ++e0) {
      int e = w * 16 + e0;
      const float* we = A.w_emb + e * 64;
      float acc = A.b_emb[e];
      #pragma unroll 8
      for (int v = 0; v < 64; ++v) acc = fmaf(we[v], SMf[b * 65 + v], acc);
      dst[e * 64 + b] = acc;
    }
  }
  gridbar_flush(bar, ep);

  const int lenb = A.seqlens[bq];

#define KSTAGE(TILE, BUFI) { \
  const float* kgp_ = A.enc_key + (size_t)bq * 262144 + (size_t)(ch * 512 + (TILE) * 128) * 128; \
  float* dst_ = SMf + (BUFI) * 16384; \
  _Pragma("unroll") for (int s_ = 0; s_ < 4; ++s_) { \
    int i2_ = w * 4 + s_; int rr_ = 2 * i2_ + (lane >> 5); \
    gl16n(kgp_ + rr_ * 128 + (((lane & 31) ^ (rr_ & 7)) << 2), dst_ + i2_ * 256); } }
#define VSTAGE(TILE, BUFI) { \
  const float* vgp_ = A.value + (size_t)bq * 262144 + (size_t)(ch * 512 + (TILE) * 128) * 128; \
  float* dst_ = SMf + (BUFI) * 16384; \
  _Pragma("unroll") for (int s_ = 0; s_ < 4; ++s_) { \
    int i2_ = w * 4 + s_; \
    gl16n(vgp_ + i2_ * 256 + lane * 4, dst_ + i2_ * 256); } }

  // ===== main recurrence: 4 fence-free barriers/step =====
  #pragma unroll 1
  for (int t = 0; t < 256; ++t) {
    const int p = t & 1;

    // ---- 3 LSTM phases: 64 rg x 4 bg, full K per block, no cross-block reduce ----
    #pragma unroll 1
    for (int l = 0; l < 3; ++l) {
      const int NT = (l == 0) ? 7 : 8;
      float* XL  = SMf;             // [K][17]
      float* WL0 = SMf + 17408;     // [128][32] swizzled
      float* WL1 = SMf + 21504;
      float* RED = SMf + 25600;     // [16][128]

      const float* wpk = (l == 0) ? (WPACK + rg * 28672)
                       : (l == 1) ? (WPACK + WP1 + rg * 32768)
                                  : (WPACK + WP2 + rg * 32768);
      // issue weight tile 0
      gl16n(wpk + w * 256 + lane * 4, WL0 + w * 256);

      // stage x quarter-batch into XL[k*17 + bl]
      if (l == 0) {
        const float* xe = XEMB + t * 16384;
        const float* ct = CTX + t * 8192;
        const float* h0 = HSb + p * 32768;
        #pragma unroll 2
        for (int m = 0; m < 14; ++m) {
          int idx = tid + m * 1024;
          int k = idx >> 4, bl = idx & 15;
          int bgl = bg * 16 + bl;
          float v;
          if (k < 256)      v = xe[k * 64 + bgl];
          else if (k < 384) v = AL(ct + (k - 256) * 64 + bgl);
          else              v = AL(h0 + (k - 384) * 64 + bgl);
          XL[k * 17 + bl] = v;
        }
      } else {
        const float* hin = HSb + ((l - 1) * 2 + (p ^ 1)) * 32768;
        const float* hpr = HSb + (l * 2 + p) * 32768;
        #pragma unroll 2
        for (int m = 0; m < 16; ++m) {
          int idx = tid + m * 1024;
          int k = idx >> 4, bl = idx & 15;
          int bgl = bg * 16 + bl;
          float v = (k < 512) ? AL(hin + k * 64 + bgl) : AL(hpr + (k - 512) * 64 + bgl);
          XL[k * 17 + bl] = v;
        }
      }

      const int g = w >> 2, kshi = w & 3;
      const int kslo = lane >> 3, bp = lane & 7;
      const int ks = kshi * 8 + kslo;     // 0..31
      float acc[16];
      #pragma unroll
      for (int i = 0; i < 16; ++i) acc[i] = 0.f;

      WAITV(0);
      __syncthreads();

      #pragma unroll 1
      for (int tile = 0; tile < NT; ++tile) {
        float* WLc = (tile & 1) ? WL1 : WL0;
        if (tile + 1 < NT) {
          float* WLn = ((tile + 1) & 1) ? WL1 : WL0;
          gl16n(wpk + (tile + 1) * 4096 + w * 256 + lane * 4, WLn + w * 256);
          WAITV(1);           // current tile (older) now complete
        } else {
          WAITV(0);
        }
        __syncthreads();
        #pragma unroll
        for (int i = 0; i < 4; ++i) {
          int k = ks + 32 * i;
          int sw = (k & 7) << 2;
          const float* wb = WLc + k * 32;
          float4 wa = *(const float4*)&wb[(g * 8) ^ sw];
          float4 wv = *(const float4*)&wb[(g * 8 + 4) ^ sw];
          float x0 = XL[(tile * 128 + k) * 17 + bp * 2];
          float x1 = XL[(tile * 128 + k) * 17 + bp * 2 + 1];
          acc[0]  = fmaf(wa.x, x0, acc[0]);  acc[1]  = fmaf(wa.x, x1, acc[1]);
          acc[2]  = fmaf(wa.y, x0, acc[2]);  acc[3]  = fmaf(wa.y, x1, acc[3]);
          acc[4]  = fmaf(wa.z, x0, acc[4]);  acc[5]  = fmaf(wa.z, x1, acc[5]);
          acc[6]  = fmaf(wa.w, x0, acc[6]);  acc[7]  = fmaf(wa.w, x1, acc[7]);
          acc[8]  = fmaf(wv.x, x0, acc[8]);  acc[9]  = fmaf(wv.x, x1, acc[9]);
          acc[10] = fmaf(wv.y, x0, acc[10]); acc[11] = fmaf(wv.y, x1, acc[11]);
          acc[12] = fmaf(wv.z, x0, acc[12]); acc[13] = fmaf(wv.z, x1, acc[13]);
          acc[14] = fmaf(wv.w, x0, acc[14]); acc[15] = fmaf(wv.w, x1, acc[15]);
        }
        __syncthreads();
      }
      // in-wave butterfly over k-split lanes (lane bits 3..5)
      #pragma unroll
      for (int d = 8; d <= 32; d <<= 1) {
        #pragma unroll
        for (int i = 0; i < 16; ++i) acc[i] += __shfl_xor(acc[i], d);
      }
      if (kslo == 0) {
        #pragma unroll
        for (int i = 0; i < 16; ++i)
          RED[(g * 4 + kshi) * 128 + bp * 16 + i] = acc[i];
      }
      __syncthreads();
      if (tid < 128) {
        int jl = tid >> 4, bl = tid & 15;
        int j = rg * 8 + jl;
        int bgl = bg * 16 + bl;
        int ri = (bl >> 1) * 16 + jl * 2 + (bl & 1);
        float v0 = 0.f, v1 = 0.f, v2 = 0.f, v3 = 0.f;
        #pragma unroll
        for (int kh = 0; kh < 4; ++kh) {
          v0 += RED[(0 * 4 + kh) * 128 + ri];
          v1 += RED[(1 * 4 + kh) * 128 + ri];
          v2 += RED[(2 * 4 + kh) * 128 + ri];
          v3 += RED[(3 * 4 + kh) * 128 + ri];
        }
        float gi = v0 + BC[l * 2048 + j];
        float gf = v1 + BC[l * 2048 + 512 + j];
        float gG = v2 + BC[l * 2048 + 1024 + j];
        float go = v3 + BC[l * 2048 + 1536 + j];
        float cprev = AL(CSb + (l * 2 + p) * 32768 + j * 64 + bgl);
        float c2 = sigmoidf_(gf) * cprev + sigmoidf_(gi) * tanhf(gG);
        float h2 = sigmoidf_(go) * tanhf(c2);
        AS(CSb + (l * 2 + (p ^ 1)) * 32768 + j * 64 + bgl, c2);
        AS(HSb + (l * 2 + (p ^ 1)) * 32768 + j * 64 + bgl, h2);
        if (l == 2) AS(HT + (p ^ 1) * 32768 + bgl * 512 + j, h2);
      }
      gridbar_fast(bar, ep);
    }

    // ---- ATTN: block=(bq,ch); K/V streamed double-buffered; quad combine ----
    {
      float* H2C = SMf + 32768;
      float* QP  = SMf + 33280;
      float* QV  = SMf + 34304;
      float* ZS  = SMf + 34432;
      float* MR  = SMf + 34944;
      float* PR  = SMf + 34976;

      KSTAGE(0, 0); KSTAGE(1, 1);
      float h2v = 0.f;
      if (tid < 512) h2v = AL(HT + (p ^ 1) * 32768 + bq * 512 + tid);
      WAITV(0); SBAR;
      if (tid < 512) H2C[tid] = h2v;
      __syncthreads();
      // q = WFCT^T h2 + b_fc
      {
        int kv = tid & 127, jg = tid >> 7;
        const float* wf = WFCT + (jg * 64) * 128 + kv;
        float pa = 0.f;
        #pragma unroll 8
        for (int jl = 0; jl < 64; ++jl) pa = fmaf(wf[jl * 128], H2C[jg * 64 + jl], pa);
        QP[jg * 128 + kv] = pa;
      }
      __syncthreads();
      if (tid < 128) {
        float qv = A.b_fc[tid];
        #pragma unroll
        for (int g = 0; g < 8; ++g) qv += QP[g * 128 + tid];
        QV[tid] = qv;
        if (ch == 0) QA[t * 8192 + tid * 64 + bq] = qv;
      }
      __syncthreads();

      // energy over 4 K tiles
      #pragma unroll 1
      for (int tu = 0; tu < 4; ++tu) {
        {
          int tl = tid & 127, kq = tid >> 7, rot = tl & 7;
          const float* KB = SMf + (tu & 1) * 16384 + tl * 128;
          float e = 0.f;
          #pragma unroll
          for (int gi = 0; gi < 4; ++gi) {
            int g = kq * 4 + gi, slot = g ^ rot;
            float4 k4 = *(const float4*)&KB[slot * 4];
            float4 q4 = *(const float4*)&QV[g * 4];
            e += k4.x * q4.x + k4.y * q4.y + k4.z * q4.z + k4.w * q4.w;
          }
          QP[kq * 128 + tl] = e;
        }
        __syncthreads();
        if (tu == 0)      { KSTAGE(2, 0); }
        else if (tu == 1) { KSTAGE(3, 1); }
        else if (tu == 2) { VSTAGE(0, 0); }
        else              { VSTAGE(1, 1); }
        if (tid < 128) {
          float ee = 0.f;
          #pragma unroll
          for (int g = 0; g < 8; ++g) ee += QP[g * 128 + tid];
          int ta = ch * 512 + tu * 128 + tid;
          ZS[tu * 128 + tid] = (ta < lenb) ? ee : 0.0f;   // energy * mask
        }
        if (tu < 3) { WAITV(4); }
        __syncthreads();
      }
      // chunk softmax over 512
      float z = (tid < 512) ? ZS[tid] : -3.0e38f;
      float mm = z;
      #pragma unroll
      for (int d = 1; d < 64; d <<= 1) mm = fmaxf(mm, __shfl_xor(mm, d));
      if (lane == 0 && w < 8) MR[w] = mm;
      __syncthreads();
      mm = MR[0];
      #pragma unroll
      for (int i2 = 1; i2 < 8; ++i2) mm = fmaxf(mm, MR[i2]);
      float ex = 0.f;
      if (tid < 512) { ex = expf(z - mm); ZS[tid] = ex; }
      float ss = ex;
      #pragma unroll
      for (int d = 1; d < 64; d <<= 1) ss += __shfl_xor(ss, d);
      if (lane == 0 && w < 8) MR[8 + w] = ss;
      __syncthreads();
      float S = 0.f;
      #pragma unroll
      for (int i2 = 0; i2 < 8; ++i2) S += MR[8 + i2];
      const float m_ch = mm;
      if (tid == 0) {
        AS(MSQ + bq * 8 + ch * 2, m_ch);
        AS(MSQ + bq * 8 + ch * 2 + 1, S);
      }
      // PV over 4 V tiles
      float c0 = 0.f, c1 = 0.f, c2a = 0.f, c3 = 0.f;
      const int tg = tid >> 5, kv4 = (tid & 31) * 4;
      #pragma unroll 1
      for (int vt = 0; vt < 4; ++vt) {
        if (vt < 3) { WAITV(4); } else { WAITV(0); }
        __syncthreads();
        const float* B = SMf + (vt & 1) * 16384;
        #pragma unroll
        for (int i2 = 0; i2 < 4; ++i2) {
          int r = tg * 4 + i2;
          float a = ZS[vt * 128 + r];
          float4 v4 = *(const float4*)&B[r * 128 + kv4];
          c0 = fmaf(a, v4.x, c0); c1 = fmaf(a, v4.y, c1);
          c2a = fmaf(a, v4.z, c2a); c3 = fmaf(a, v4.w, c3);
        }
        __syncthreads();
        if (vt == 0)      { VSTAGE(2, 0); }
        else if (vt == 1) { VSTAGE(3, 1); }
      }
      PR[tg * 128 + kv4]     = c0;
      PR[tg * 128 + kv4 + 1] = c1;
      PR[tg * 128 + kv4 + 2] = c2a;
      PR[tg * 128 + kv4 + 3] = c3;
      __syncthreads();
      float ownpart = 0.f;
      if (tid < 128) {
        float s = 0.f;
        #pragma unroll
        for (int g2 = 0; g2 < 32; ++g2) s += PR[g2 * 128 + tid];
        ownpart = s;
        AS(CTXQ + bq * 512 + ch * 128 + tid, s);
      }
      WAITV(0);
      __syncthreads();
      // quad-team micro-barrier
      if (tid == 0) {
        int* qc = qbar + bq * 8;
        __hip_atomic_fetch_add(qc, 1, __ATOMIC_RELAXED, __HIP_MEMORY_SCOPE_AGENT);
        while (__hip_atomic_load(qc, __ATOMIC_RELAXED, __HIP_MEMORY_SCOPE_AGENT) < eA * 4)
          __builtin_amdgcn_s_sleep(1);
      }
      __syncthreads();
      ++eA;
      if (tid < 8) MR[16 + tid] = AL(MSQ + bq * 8 + tid);
      __syncthreads();
      float mall = fmaxf(fmaxf(MR[16], MR[18]), fmaxf(MR[20], MR[22]));
      float Z = MR[17] * expf(MR[16] - mall) + MR[19] * expf(MR[18] - mall)
              + MR[21] * expf(MR[20] - mall) + MR[23] * expf(MR[22] - mall);
      float invZ = 1.0f / Z;
      if (tid < 512)
        ATTS[(size_t)(t & 63) * 512 + tid] = ZS[tid] * (expf(m_ch - mall) * invZ);
      if (ch == 0 && tid < 128) {
        float q1 = AL(CTXQ + bq * 512 + 128 + tid);
        float q2 = AL(CTXQ + bq * 512 + 256 + tid);
        float q3 = AL(CTXQ + bq * 512 + 384 + tid);
        float f0 = expf(MR[16] - mall) * invZ;
        float f1 = expf(MR[18] - mall) * invZ;
        float f2 = expf(MR[20] - mall) * invZ;
        float f3 = expf(MR[22] - mall) * invZ;
        AS(CTX + (t + 1) * 8192 + tid * 64 + bq,
           ownpart * f0 + q1 * f1 + q2 * f2 + q3 * f3);
      }
      // coalesced NT flush of attentions every 64 steps
      if ((t & 63) == 63) {
        __syncthreads();
        if (tid < 512) {
          float* o4 = out4 + (size_t)bq * 524288 + (size_t)(ch * 512 + tid) * 256 + (t - 63);
          const float* sst = ATTS + tid;
          #pragma unroll 4
          for (int q4i = 0; q4i < 16; ++q4i) {
            nf4 v;
            v.x = sst[(size_t)(q4i * 4 + 0) * 512];
            v.y = sst[(size_t)(q4i * 4 + 1) * 512];
            v.z = sst[(size_t)(q4i * 4 + 2) * 512];
            v.w = sst[(size_t)(q4i * 4 + 3) * 512];
            __builtin_nontemporal_store(v, (nf4*)(o4 + q4i * 4));
          }
        }
      }
    }
    gridbar_fast(bar, ep);
  }

  gridbar_flush(bar, ep);

  // ===== Epilogue: MLP head + argmax (block = one t) =====
  {
    const int t = blk;
    const int sl = w, b = lane;
    const float* qa_t = QA + t * 8192;
    const float* ct1 = CTX + (t + 1) * 8192;
    #pragma unroll
    for (int i = 0; i < 8; ++i) {
      int idx = tid + i * 1024;
      SMf[(idx >> 6) * 65 + (idx & 63)] = qa_t[idx];
      SMf[(128 + (idx >> 6)) * 65 + (idx & 63)] = ct1[idx];
    }
    __syncthreads();
    float a1[16];
    #pragma unroll
    for (int i = 0; i < 16; ++i) a1[i] = 0.f;
    const float* w1 = A.w_mlp1 + (sl * 16) * 256;
    #pragma unroll 2
    for (int k = 0; k < 256; ++k) {
      float xv = SMf[k * 65 + b];
      #pragma unroll
      for (int m2 = 0; m2 < 16; ++m2) a1[m2] = fmaf(w1[m2 * 256 + k], xv, a1[m2]);
    }
    float* ACT = SMf + 16640;
    #pragma unroll
    for (int m2 = 0; m2 < 16; ++m2) {
      float v2 = a1[m2] + A.b_mlp1[sl * 16 + m2];
      ACT[(sl * 16 + m2) * 65 + b] = (v2 >= 0.f) ? v2 : 0.9f * v2;   // LeakyReLU(0.9)
    }
    __syncthreads();
    float y[4] = {0.f, 0.f, 0.f, 0.f};
    const float* w2 = A.w_mlp2 + (sl * 4) * 256;
    #pragma unroll 2
    for (int k = 0; k < 256; ++k) {
      float xv = ACT[k * 65 + b];
      #pragma unroll
      for (int m2 = 0; m2 < 4; ++m2) y[m2] = fmaf(w2[m2 * 256 + k], xv, y[m2]);
    }
    #pragma unroll
    for (int m2 = 0; m2 < 4; ++m2) y[m2] += A.b_mlp2[sl * 4 + m2];
    *(float4*)(out0 + b * 16384 + t * 64 + sl * 4) = make_float4(y[0], y[1], y[2], y[3]);
    __syncthreads();
    float* YB = SMf + 34976;
    #pragma unroll
    for (int m2 = 0; m2 < 4; ++m2) YB[(sl * 4 + m2) * 65 + b] = y[m2];
    __syncthreads();
    if (tid < 64) {
      float best = YB[tid];
      int bi = 0;
      #pragma unroll 1
      for (int v = 1; v < 64; ++v) {
        float val = YB[v * 65 + tid];
        if (val > best) { best = val; bi = v; }   // first-occurrence argmax
      }
      out1[tid * 256 + t] = (float)bi;
    }
  }
}

extern "C" void kernel_launch(void* const* d_in, const int* in_sizes, int n_in,
                              void* d_out, int out_size, void* d_ws, size_t ws_size,
                              hipStream_t stream) {
  if (ws_size < (size_t)WS_TOTAL * 4) return;   // ~93.6 MB scratch
  KArgs a;
  a.enc_key = (const float*)d_in[0];
  a.value   = (const float*)d_in[1];
  a.labels  = (const int*)d_in[2];
  a.seqlens = (const int*)d_in[3];
  a.sos     = (const int*)d_in[4];
  a.w_emb  = (const float*)d_in[6];  a.b_emb  = (const float*)d_in[7];
  a.w_ih0  = (const float*)d_in[8];  a.w_hh0  = (const float*)d_in[9];
  a.b_ih0  = (const float*)d_in[10]; a.b_hh0  = (const float*)d_in[11];
  a.w_ih1  = (const float*)d_in[12]; a.w_hh1  = (const float*)d_in[13];
  a.b_ih1  = (const float*)d_in[14]; a.b_hh1  = (const float*)d_in[15];
  a.w_ih2  = (const float*)d_in[16]; a.w_hh2  = (const float*)d_in[17];
  a.b_ih2  = (const float*)d_in[18]; a.b_hh2  = (const float*)d_in[19];
  a.w_fc   = (const float*)d_in[20]; a.b_fc   = (const float*)d_in[21];
  a.w_mlp1 = (const float*)d_in[22]; a.b_mlp1 = (const float*)d_in[23];
  a.w_mlp2 = (const float*)d_in[24]; a.b_mlp2 = (const float*)d_in[25];
  a.out = (float*)d_out;
  a.ws  = (float*)d_ws;

  int* bar = (int*)((float*)d_ws + OF_BAR);
  hipLaunchKernelGGL(bar_init_kernel, dim3(1), dim3(1024), 0, stream, bar);

  void* args[] = { (void*)&a };
  hipLaunchCooperativeKernel(reinterpret_cast<void*>(dec_kernel),
                             dim3(256), dim3(1024), args, 0, stream);
}

// Round 10
// 28203.546 us; speedup vs baseline: 1.8554x; 1.0198x over previous
//
#include <hip/hip_runtime.h>

typedef unsigned int u32;
typedef float nf4 __attribute__((ext_vector_type(4)));
#define DEVI __device__ __forceinline__

// ---- JAX threefry2x32 (exact) ----
DEVI void tf2x32(u32 k0, u32 k1, u32 x0, u32 x1, u32& o0, u32& o1) {
  u32 ks2 = k0 ^ k1 ^ 0x1BD11BDAu;
  x0 += k0; x1 += k1;
#define TFR(r) { x0 += x1; x1 = (x1 << (r)) | (x1 >> (32 - (r))); x1 ^= x0; }
  TFR(13) TFR(15) TFR(26) TFR(6)
  x0 += k1; x1 += ks2 + 1u;
  TFR(17) TFR(29) TFR(16) TFR(24)
  x0 += ks2; x1 += k0 + 2u;
  TFR(13) TFR(15) TFR(26) TFR(6)
  x0 += k0; x1 += k1 + 3u;
  TFR(17) TFR(29) TFR(16) TFR(24)
  x0 += k1; x1 += ks2 + 4u;
  TFR(13) TFR(15) TFR(26) TFR(6)
  x0 += ks2; x1 += k0 + 5u;
#undef TFR
  o0 = x0; o1 = x1;
}

DEVI float jax_uniform(u32 k0, u32 k1, u32 idx) {
  u32 a, b; tf2x32(k0, k1, 0u, idx, a, b);
  u32 bits = a ^ b;
  return __uint_as_float((bits >> 9) | 0x3F800000u) - 1.0f;
}

DEVI float sigmoidf_(float x) { return 1.0f / (1.0f + expf(-x)); }

// ---- validated coherence primitives (R3/R4/R9-proven) ----
DEVI float AL(const float* p) {
  return __hip_atomic_load((float*)p, __ATOMIC_RELAXED, __HIP_MEMORY_SCOPE_AGENT);
}
DEVI void AS(float* p, float v) {
  __hip_atomic_store(p, v, __ATOMIC_RELAXED, __HIP_MEMORY_SCOPE_AGENT);
}

// async global->LDS (IMMUTABLE data only), plain cached
typedef const __attribute__((address_space(1))) u32* gas1;
typedef __attribute__((address_space(3))) u32* las3;
DEVI void gl16n(const float* g, float* l) { __builtin_amdgcn_global_load_lds((gas1)g, (las3)l, 16, 0, 0); }
#define WAITV(N) asm volatile("s_waitcnt vmcnt(" #N ")" ::: "memory")
#define SBAR __builtin_amdgcn_sched_barrier(0)

struct KArgs {
  const float* enc_key; const float* value;
  const int* labels; const int* seqlens; const int* sos;
  const float* w_emb; const float* b_emb;
  const float* w_ih0; const float* w_hh0; const float* b_ih0; const float* b_hh0;
  const float* w_ih1; const float* w_hh1; const float* b_ih1; const float* b_hh1;
  const float* w_ih2; const float* w_hh2; const float* b_ih2; const float* b_hh2;
  const float* w_fc; const float* b_fc;
  const float* w_mlp1; const float* b_mlp1;
  const float* w_mlp2; const float* b_mlp2;
  float* out; float* ws;
};

// ws offsets (floats)
#define OF_Y0     0         // 4096
#define OF_XEMB   4096      // 256*16384
#define OF_HSB    4198400   // [3][2][512][64]
#define OF_CSB    4395008
#define OF_CTX    4591616   // [257][128][64]
#define OF_CTXQ   6696960   // [64][4][128]
#define OF_MSQ    6729728   // [64][4][2]
#define OF_QA     6730240   // [256][128][64]
#define OF_WPK    8827392   // packed swizzled LSTM weights per rg
#define OF_WFCT   14856704  // [512][128]
#define OF_BC     14922240  // [3][2048]
#define OF_HT     14928384  // [2][64][512]
#define OF_BAR    14993920  // 4096 ints
#define OF_QBAR   14998016  // 1024 ints
#define OF_ATT    14999040  // [256][64][512]
#define WS_TOTAL  23387648
#define WP1 1835008
#define WP2 3932160

// fence-free two-level grid barrier (R3/R4/R9-proven)
DEVI void bar_arrive_wait(int* bar, int& ep) {
  if (threadIdx.x == 0) {
    int g = (int)(blockIdx.x & 15);
    int old = __hip_atomic_fetch_add(bar + g * 64, 1, __ATOMIC_RELAXED, __HIP_MEMORY_SCOPE_AGENT);
    if (old == ep * 16 - 1) {
      int o2 = __hip_atomic_fetch_add(bar + 1024, 1, __ATOMIC_RELAXED, __HIP_MEMORY_SCOPE_AGENT);
      if (o2 == ep * 16 - 1) {
        #pragma unroll
        for (int gg = 0; gg < 16; ++gg)
          __hip_atomic_store(bar + 2048 + gg * 64, ep, __ATOMIC_RELAXED, __HIP_MEMORY_SCOPE_AGENT);
      }
    }
    while (__hip_atomic_load(bar + 2048 + g * 64, __ATOMIC_RELAXED, __HIP_MEMORY_SCOPE_AGENT) < ep)
      __builtin_amdgcn_s_sleep(1);
  }
  __syncthreads();
  ++ep;
}
DEVI void gridbar_fast(int* bar, int& ep) {
  WAITV(0);
  __syncthreads();
  bar_arrive_wait(bar, ep);
}
DEVI void gridbar_flush(int* bar, int& ep) {
  WAITV(0);
  __syncthreads();
  if (threadIdx.x == 0) __threadfence();
  __syncthreads();
  bar_arrive_wait(bar, ep);
  if (threadIdx.x == 0) __threadfence();
  __syncthreads();
}

__global__ void bar_init_kernel(int* bar) {
  for (int i = 0; i < 5; ++i) {
    int idx = threadIdx.x + i * 1024;
    if (idx < 5120) bar[idx] = 0;
  }
}

// B=64 TK=2048 TL=256 V=64 E=256 KV=128 H=512 MH=256
__global__ __launch_bounds__(1024, 1) void dec_kernel(KArgs A) {
  const int blk = blockIdx.x;
  const int tid = threadIdx.x;
  const int lane = tid & 63;
  const int w = tid >> 6;

  float* const Y0   = A.ws + OF_Y0;
  float* const XEMB = A.ws + OF_XEMB;
  float* const HSb  = A.ws + OF_HSB;
  float* const CSb  = A.ws + OF_CSB;
  float* const CTX  = A.ws + OF_CTX;
  float* const CTXQ = A.ws + OF_CTXQ;
  float* const MSQ  = A.ws + OF_MSQ;
  float* const QA   = A.ws + OF_QA;
  float* const WPACK= A.ws + OF_WPK;
  float* const WFCT = A.ws + OF_WFCT;
  float* const BC   = A.ws + OF_BC;
  float* const HT   = A.ws + OF_HT;
  int*   const bar  = (int*)(A.ws + OF_BAR);
  int*   const qbar = (int*)(A.ws + OF_QBAR);
  float* const ATTS = A.ws + OF_ATT + (size_t)blk * 32768;

  float* const out0 = A.out;
  float* const out1 = A.out + 1048576;
  float* const out2 = A.out + 1064960;
  float* const out3 = A.out + 1081344;
  float* const out4 = A.out + 2129920;

  __shared__ __align__(16) float SMf[39072];   // 156.3 KB
  int ep = 1, eA = 1;

  const int rg = blk >> 2, bg = blk & 3;   // LSTM: row-group x batch-quarter
  const int bq = rg, ch = bg;              // ATTN: batch x chunk

  u32 KA0, KA1, KB0, KB1;
  tf2x32(0u, 42u, 0u, 0u, KA0, KA1);
  tf2x32(0u, 42u, 0u, 1u, KB0, KB1);

  // ===== Prologue =====
  if (bg == 0) {
    for (int idx = tid; idx < 28672; idx += 1024) {         // l0: 7 tiles
      int tile = idx >> 12, rem = idx & 4095;
      int k = rem >> 5, slot = rem & 31;
      int pr = slot ^ ((k & 7) << 2);
      int g = pr >> 3, jj = pr & 7;
      int R = g * 512 + rg * 8 + jj;
      int gk = tile * 128 + k;
      WPACK[rg * 28672 + idx] = (gk < 384) ? A.w_ih0[R * 384 + gk] : A.w_hh0[R * 512 + gk - 384];
    }
    for (int idx = tid; idx < 32768; idx += 1024) {         // l1: 8 tiles
      int tile = idx >> 12, rem = idx & 4095;
      int k = rem >> 5, slot = rem & 31;
      int pr = slot ^ ((k & 7) << 2);
      int g = pr >> 3, jj = pr & 7;
      int R = g * 512 + rg * 8 + jj;
      int gk = tile * 128 + k;
      WPACK[WP1 + rg * 32768 + idx] = (gk < 512) ? A.w_ih1[R * 512 + gk] : A.w_hh1[R * 512 + gk - 512];
    }
    for (int idx = tid; idx < 32768; idx += 1024) {         // l2
      int tile = idx >> 12, rem = idx & 4095;
      int k = rem >> 5, slot = rem & 31;
      int pr = slot ^ ((k & 7) << 2);
      int g = pr >> 3, jj = pr & 7;
      int R = g * 512 + rg * 8 + jj;
      int gk = tile * 128 + k;
      WPACK[WP2 + rg * 32768 + idx] = (gk < 512) ? A.w_ih2[R * 512 + gk] : A.w_hh2[R * 512 + gk - 512];
    }
  }
  if (blk < 65) {
    int slot = blk * 1024 + tid;
    int r = slot >> 2, q = slot & 3;
    if (r < 16448) {
      bool isY0 = (r >= 16384);
      int t = 0, b, label;
      u32 key0, key1, base;
      if (!isY0) {
        t = r >> 6; b = r & 63;
        label = A.labels[t * 64 + b];
        key0 = KA0; key1 = KA1; base = (u32)(r * 64);
      } else {
        b = r - 16384;
        label = A.sos[0];
        key0 = KB0; key1 = KB1; base = (u32)(b * 64);
      }
      float sv[16];
      float mx = -3.0e38f;
      #pragma unroll
      for (int j = 0; j < 16; ++j) {
        int v = (q << 4) + j;
        float u = jax_uniform(key0, key1, base + (u32)v);
        float inner = -logf(u + 1e-10f) + 1e-10f;
        float noise = -logf(inner);
        float s = noise + ((v == label) ? 1.0f : 0.0f);
        sv[j] = s; mx = fmaxf(mx, s);
      }
      mx = fmaxf(mx, __shfl_xor(mx, 1));
      mx = fmaxf(mx, __shfl_xor(mx, 2));
      float sum = 0.f;
      #pragma unroll
      for (int j = 0; j < 16; ++j) { sv[j] = expf(sv[j] - mx); sum += sv[j]; }
      sum += __shfl_xor(sum, 1);
      sum += __shfl_xor(sum, 2);
      float inv = 1.0f / sum;
      if (!isY0) {
        #pragma unroll
        for (int j = 0; j < 16; ++j) {
          int v = (q << 4) + j;
          out3[b * 16384 + t * 64 + v] = sv[j] * inv;
        }
        if (q == 0) out2[b * 256 + t] = (float)label;
      } else {
        #pragma unroll
        for (int j = 0; j < 16; ++j) Y0[b * 64 + (q << 4) + j] = sv[j] * inv;
      }
    }
  } else if (blk < 128) {
    const int total1 = 401408, total2 = 401408 + 65536;   // zero h/c/ctx0 + WFCT
    for (int idx = (blk - 65) * 1024 + tid; idx < total2; idx += 63 * 1024) {
      if (idx < total1) HSb[idx] = 0.f;
      else {
        int i2 = idx - total1;
        int kv = i2 >> 9, j = i2 & 511;
        WFCT[j * 128 + kv] = A.w_fc[kv * 512 + j];
      }
    }
  } else if (blk == 255) {
    for (int idx = tid; idx < 6144; idx += 1024) {
      int l = idx >> 11, r = idx & 2047;
      const float* bi = (l == 0) ? A.b_ih0 : (l == 1) ? A.b_ih1 : A.b_ih2;
      const float* bh = (l == 0) ? A.b_hh0 : (l == 1) ? A.b_hh1 : A.b_hh2;
      BC[idx] = bi[r] + bh[r];
    }
  }
  gridbar_flush(bar, ep);

  // ===== P1: embeddings XEMB[t][e][b] (src = out3 / Y0) =====
  {
    const int t = blk;
    #pragma unroll
    for (int i = 0; i < 4; ++i) {
      int idx = tid + i * 1024;
      int b = idx >> 6, v = idx & 63;
      float sval = (t == 0) ? Y0[idx] : out3[b * 16384 + (t - 1) * 64 + v];
      SMf[b * 65 + v] = sval;
    }
    __syncthreads();
    const int b = lane;
    float* dst = XEMB + t * 16384;
    #pragma unroll 1
    for (int e0 = 0; e0 < 16; ++e0) {
      int e = w * 16 + e0;
      const float* we = A.w_emb + e * 64;
      float acc = A.b_emb[e];
      #pragma unroll 8
      for (int v = 0; v < 64; ++v) acc = fmaf(we[v], SMf[b * 65 + v], acc);
      dst[e * 64 + b] = acc;
    }
  }
  gridbar_flush(bar, ep);

  const int lenb = A.seqlens[bq];

#define KSTAGE(TILE, BUFI) { \
  const float* kgp_ = A.enc_key + (size_t)bq * 262144 + (size_t)(ch * 512 + (TILE) * 128) * 128; \
  float* dst_ = SMf + (BUFI) * 16384; \
  _Pragma("unroll") for (int s_ = 0; s_ < 4; ++s_) { \
    int i2_ = w * 4 + s_; int rr_ = 2 * i2_ + (lane >> 5); \
    gl16n(kgp_ + rr_ * 128 + (((lane & 31) ^ (rr_ & 7)) << 2), dst_ + i2_ * 256); } }
#define VSTAGE(TILE, BUFI) { \
  const float* vgp_ = A.value + (size_t)bq * 262144 + (size_t)(ch * 512 + (TILE) * 128) * 128; \
  float* dst_ = SMf + (BUFI) * 16384; \
  _Pragma("unroll") for (int s_ = 0; s_ < 4; ++s_) { \
    int i2_ = w * 4 + s_; \
    gl16n(vgp_ + i2_ * 256 + lane * 4, dst_ + i2_ * 256); } }

  // ===== main recurrence: 4 fence-free barriers/step =====
  #pragma unroll 1
  for (int t = 0; t < 256; ++t) {
    const int p = t & 1;

    // ---- 3 LSTM phases: 64 rg x 4 bg, full K per block ----
    #pragma unroll 1
    for (int l = 0; l < 3; ++l) {
      const int NT = (l == 0) ? 7 : 8;
      float* XL  = SMf;             // [K][17]
      float* WL0 = SMf + 17408;     // [128][32] swizzled
      float* WL1 = SMf + 21504;
      float* RED = SMf + 25600;     // [16][128]

      const float* wpk = (l == 0) ? (WPACK + rg * 28672)
                       : (l == 1) ? (WPACK + WP1 + rg * 32768)
                                  : (WPACK + WP2 + rg * 32768);

      // --- batched x loads into registers (all in flight at once) ---
      float xr[16];
      if (l == 0) {
        const float* xe = XEMB + t * 16384;
        const float* ct = CTX + t * 8192;
        const float* h0 = HSb + p * 32768;
        #pragma unroll
        for (int m = 0; m < 14; ++m) {
          int idx = tid + m * 1024;
          int k = idx >> 4, bl = idx & 15;
          int bgl = bg * 16 + bl;
          xr[m] = (k < 256) ? xe[k * 64 + bgl]
                : (k < 384) ? AL(ct + (k - 256) * 64 + bgl)
                            : AL(h0 + (k - 384) * 64 + bgl);
        }
      } else {
        const float* hin = HSb + ((l - 1) * 2 + (p ^ 1)) * 32768;
        const float* hpr = HSb + (l * 2 + p) * 32768;
        #pragma unroll
        for (int m = 0; m < 16; ++m) {
          int idx = tid + m * 1024;
          int k = idx >> 4, bl = idx & 15;
          int bgl = bg * 16 + bl;
          xr[m] = (k < 512) ? AL(hin + k * 64 + bgl) : AL(hpr + (k - 512) * 64 + bgl);
        }
      }
      SBAR;
      // weight tiles 0,1 issued AFTER x loads (vmcnt ordering)
      gl16n(wpk + w * 256 + lane * 4, WL0 + w * 256);
      gl16n(wpk + 4096 + w * 256 + lane * 4, WL1 + w * 256);
      WAITV(2); SBAR;       // xr done; weight tiles in flight
      if (l == 0) {
        #pragma unroll
        for (int m = 0; m < 14; ++m) {
          int idx = tid + m * 1024;
          XL[(idx >> 4) * 17 + (idx & 15)] = xr[m];
        }
      } else {
        #pragma unroll
        for (int m = 0; m < 16; ++m) {
          int idx = tid + m * 1024;
          XL[(idx >> 4) * 17 + (idx & 15)] = xr[m];
        }
      }
      __syncthreads();

      const int g = w >> 2, kshi = w & 3;
      const int kslo = lane >> 3, bp = lane & 7;
      const int ks = kshi * 8 + kslo;     // 0..31
      float acc[16];
      #pragma unroll
      for (int i = 0; i < 16; ++i) acc[i] = 0.f;

      #pragma unroll 1
      for (int tile = 0; tile < NT; ++tile) {
        float* WLc = (tile & 1) ? WL1 : WL0;
        if (tile + 1 < NT) { WAITV(1); } else { WAITV(0); }
        __syncthreads();
        #pragma unroll
        for (int i = 0; i < 4; ++i) {
          int k = ks + 32 * i;
          int sw = (k & 7) << 2;
          const float* wb = WLc + k * 32;
          float4 wa = *(const float4*)&wb[(g * 8) ^ sw];
          float4 wv = *(const float4*)&wb[(g * 8 + 4) ^ sw];
          float x0 = XL[(tile * 128 + k) * 17 + bp * 2];
          float x1 = XL[(tile * 128 + k) * 17 + bp * 2 + 1];
          acc[0]  = fmaf(wa.x, x0, acc[0]);  acc[1]  = fmaf(wa.x, x1, acc[1]);
          acc[2]  = fmaf(wa.y, x0, acc[2]);  acc[3]  = fmaf(wa.y, x1, acc[3]);
          acc[4]  = fmaf(wa.z, x0, acc[4]);  acc[5]  = fmaf(wa.z, x1, acc[5]);
          acc[6]  = fmaf(wa.w, x0, acc[6]);  acc[7]  = fmaf(wa.w, x1, acc[7]);
          acc[8]  = fmaf(wv.x, x0, acc[8]);  acc[9]  = fmaf(wv.x, x1, acc[9]);
          acc[10] = fmaf(wv.y, x0, acc[10]); acc[11] = fmaf(wv.y, x1, acc[11]);
          acc[12] = fmaf(wv.z, x0, acc[12]); acc[13] = fmaf(wv.z, x1, acc[13]);
          acc[14] = fmaf(wv.w, x0, acc[14]); acc[15] = fmaf(wv.w, x1, acc[15]);
        }
        __syncthreads();
        if (tile + 2 < NT) {
          float* WLn = (tile & 1) ? WL1 : WL0;    // same parity as tile
          gl16n(wpk + (tile + 2) * 4096 + w * 256 + lane * 4, WLn + w * 256);
        }
      }
      // in-wave butterfly over k-split lanes (lane bits 3..5)
      #pragma unroll
      for (int d = 8; d <= 32; d <<= 1) {
        #pragma unroll
        for (int i = 0; i < 16; ++i) acc[i] += __shfl_xor(acc[i], d);
      }
      if (kslo == 0) {
        #pragma unroll
        for (int i = 0; i < 16; ++i)
          RED[(g * 4 + kshi) * 128 + bp * 16 + i] = acc[i];
      }
      __syncthreads();
      if (tid < 128) {
        int jl = tid >> 4, bl = tid & 15;
        int j = rg * 8 + jl;
        int bgl = bg * 16 + bl;
        int ri = (bl >> 1) * 16 + jl * 2 + (bl & 1);
        float v0 = 0.f, v1 = 0.f, v2 = 0.f, v3 = 0.f;
        #pragma unroll
        for (int kh = 0; kh < 4; ++kh) {
          v0 += RED[(0 * 4 + kh) * 128 + ri];
          v1 += RED[(1 * 4 + kh) * 128 + ri];
          v2 += RED[(2 * 4 + kh) * 128 + ri];
          v3 += RED[(3 * 4 + kh) * 128 + ri];
        }
        float gi = v0 + BC[l * 2048 + j];
        float gf = v1 + BC[l * 2048 + 512 + j];
        float gG = v2 + BC[l * 2048 + 1024 + j];
        float go = v3 + BC[l * 2048 + 1536 + j];
        float cprev = AL(CSb + (l * 2 + p) * 32768 + j * 64 + bgl);
        float c2 = sigmoidf_(gf) * cprev + sigmoidf_(gi) * tanhf(gG);
        float h2 = sigmoidf_(go) * tanhf(c2);
        AS(CSb + (l * 2 + (p ^ 1)) * 32768 + j * 64 + bgl, c2);
        AS(HSb + (l * 2 + (p ^ 1)) * 32768 + j * 64 + bgl, h2);
        if (l == 2) AS(HT + (p ^ 1) * 32768 + bgl * 512 + j, h2);
      }
      if (l == 2) {
        // pre-issue K tiles 0,1 so their latency hides under the grid barrier
        __syncthreads();     // protect RED (overlaps K buf1) until tid<128 done
        KSTAGE(0, 0);
        KSTAGE(1, 1);
      }
      gridbar_fast(bar, ep);
    }

    // ---- ATTN: block=(bq,ch); K0/K1 already in LDS; quad combine ----
    {
      float* H2C = SMf + 32768;
      float* QP  = SMf + 33280;
      float* QV  = SMf + 34304;
      float* ZS  = SMf + 34432;
      float* MR  = SMf + 34944;
      float* PR  = SMf + 34976;

      float h2v = 0.f;
      if (tid < 512) h2v = AL(HT + (p ^ 1) * 32768 + bq * 512 + tid);
      WAITV(0); SBAR;
      if (tid < 512) H2C[tid] = h2v;
      __syncthreads();
      // q = WFCT^T h2 + b_fc
      {
        int kv = tid & 127, jg = tid >> 7;
        const float* wf = WFCT + (jg * 64) * 128 + kv;
        float pa = 0.f;
        #pragma unroll 8
        for (int jl = 0; jl < 64; ++jl) pa = fmaf(wf[jl * 128], H2C[jg * 64 + jl], pa);
        QP[jg * 128 + kv] = pa;
      }
      __syncthreads();
      if (tid < 128) {
        float qv = A.b_fc[tid];
        #pragma unroll
        for (int g = 0; g < 8; ++g) qv += QP[g * 128 + tid];
        QV[tid] = qv;
        if (ch == 0) QA[t * 8192 + tid * 64 + bq] = qv;
      }
      __syncthreads();

      // energy over 4 K tiles
      #pragma unroll 1
      for (int tu = 0; tu < 4; ++tu) {
        {
          int tl = tid & 127, kq = tid >> 7, rot = tl & 7;
          const float* KB = SMf + (tu & 1) * 16384 + tl * 128;
          float e = 0.f;
          #pragma unroll
          for (int gi = 0; gi < 4; ++gi) {
            int g = kq * 4 + gi, slot = g ^ rot;
            float4 k4 = *(const float4*)&KB[slot * 4];
            float4 q4 = *(const float4*)&QV[g * 4];
            e += k4.x * q4.x + k4.y * q4.y + k4.z * q4.z + k4.w * q4.w;
          }
          QP[kq * 128 + tl] = e;
        }
        __syncthreads();
        if (tu == 0)      { KSTAGE(2, 0); }
        else if (tu == 1) { KSTAGE(3, 1); }
        else if (tu == 2) { VSTAGE(0, 0); }
        else              { VSTAGE(1, 1); }
        if (tid < 128) {
          float ee = 0.f;
          #pragma unroll
          for (int g = 0; g < 8; ++g) ee += QP[g * 128 + tid];
          int ta = ch * 512 + tu * 128 + tid;
          ZS[tu * 128 + tid] = (ta < lenb) ? ee : 0.0f;   // energy * mask
        }
        if (tu < 3) { WAITV(4); }
        __syncthreads();
      }
      // chunk softmax over 512
      float z = (tid < 512) ? ZS[tid] : -3.0e38f;
      float mm = z;
      #pragma unroll
      for (int d = 1; d < 64; d <<= 1) mm = fmaxf(mm, __shfl_xor(mm, d));
      if (lane == 0 && w < 8) MR[w] = mm;
      __syncthreads();
      mm = MR[0];
      #pragma unroll
      for (int i2 = 1; i2 < 8; ++i2) mm = fmaxf(mm, MR[i2]);
      float ex = 0.f;
      if (tid < 512) { ex = expf(z - mm); ZS[tid] = ex; }
      float ss = ex;
      #pragma unroll
      for (int d = 1; d < 64; d <<= 1) ss += __shfl_xor(ss, d);
      if (lane == 0 && w < 8) MR[8 + w] = ss;
      __syncthreads();
      float S = 0.f;
      #pragma unroll
      for (int i2 = 0; i2 < 8; ++i2) S += MR[8 + i2];
      const float m_ch = mm;
      if (tid == 0) {
        AS(MSQ + bq * 8 + ch * 2, m_ch);
        AS(MSQ + bq * 8 + ch * 2 + 1, S);
      }
      // PV over 4 V tiles
      float c0 = 0.f, c1 = 0.f, c2a = 0.f, c3 = 0.f;
      const int tg = tid >> 5, kv4 = (tid & 31) * 4;
      #pragma unroll 1
      for (int vt = 0; vt < 4; ++vt) {
        if (vt < 3) { WAITV(4); } else { WAITV(0); }
        __syncthreads();
        const float* B = SMf + (vt & 1) * 16384;
        #pragma unroll
        for (int i2 = 0; i2 < 4; ++i2) {
          int r = tg * 4 + i2;
          float a = ZS[vt * 128 + r];
          float4 v4 = *(const float4*)&B[r * 128 + kv4];
          c0 = fmaf(a, v4.x, c0); c1 = fmaf(a, v4.y, c1);
          c2a = fmaf(a, v4.z, c2a); c3 = fmaf(a, v4.w, c3);
        }
        __syncthreads();
        if (vt == 0)      { VSTAGE(2, 0); }
        else if (vt == 1) { VSTAGE(3, 1); }
      }
      PR[tg * 128 + kv4]     = c0;
      PR[tg * 128 + kv4 + 1] = c1;
      PR[tg * 128 + kv4 + 2] = c2a;
      PR[tg * 128 + kv4 + 3] = c3;
      __syncthreads();
      float ownpart = 0.f;
      if (tid < 128) {
        float s = 0.f;
        #pragma unroll
        for (int g2 = 0; g2 < 32; ++g2) s += PR[g2 * 128 + tid];
        ownpart = s;
        AS(CTXQ + bq * 512 + ch * 128 + tid, s);
      }
      WAITV(0);
      __syncthreads();
      // quad-team micro-barrier
      if (tid == 0) {
        int* qc = qbar + bq * 8;
        __hip_atomic_fetch_add(qc, 1, __ATOMIC_RELAXED, __HIP_MEMORY_SCOPE_AGENT);
        while (__hip_atomic_load(qc, __ATOMIC_RELAXED, __HIP_MEMORY_SCOPE_AGENT) < eA * 4)
          __builtin_amdgcn_s_sleep(1);
      }
      __syncthreads();
      ++eA;
      if (tid < 8) MR[16 + tid] = AL(MSQ + bq * 8 + tid);
      __syncthreads();
      float mall = fmaxf(fmaxf(MR[16], MR[18]), fmaxf(MR[20], MR[22]));
      float Z = MR[17] * expf(MR[16] - mall) + MR[19] * expf(MR[18] - mall)
              + MR[21] * expf(MR[20] - mall) + MR[23] * expf(MR[22] - mall);
      float invZ = 1.0f / Z;
      if (tid < 512)
        ATTS[(size_t)(t & 63) * 512 + tid] = ZS[tid] * (expf(m_ch - mall) * invZ);
      if (ch == 0 && tid < 128) {
        float q1 = AL(CTXQ + bq * 512 + 128 + tid);
        float q2 = AL(CTXQ + bq * 512 + 256 + tid);
        float q3 = AL(CTXQ + bq * 512 + 384 + tid);
        float f0 = expf(MR[16] - mall) * invZ;
        float f1 = expf(MR[18] - mall) * invZ;
        float f2 = expf(MR[20] - mall) * invZ;
        float f3 = expf(MR[22] - mall) * invZ;
        AS(CTX + (t + 1) * 8192 + tid * 64 + bq,
           ownpart * f0 + q1 * f1 + q2 * f2 + q3 * f3);
      }
      // coalesced NT flush of attentions every 64 steps
      if ((t & 63) == 63) {
        __syncthreads();
        if (tid < 512) {
          float* o4 = out4 + (size_t)bq * 524288 + (size_t)(ch * 512 + tid) * 256 + (t - 63);
          const float* sst = ATTS + tid;
          #pragma unroll 4
          for (int q4i = 0; q4i < 16; ++q4i) {
            nf4 v;
            v.x = sst[(size_t)(q4i * 4 + 0) * 512];
            v.y = sst[(size_t)(q4i * 4 + 1) * 512];
            v.z = sst[(size_t)(q4i * 4 + 2) * 512];
            v.w = sst[(size_t)(q4i * 4 + 3) * 512];
            __builtin_nontemporal_store(v, (nf4*)(o4 + q4i * 4));
          }
        }
      }
    }
    gridbar_fast(bar, ep);
  }

  gridbar_flush(bar, ep);

  // ===== Epilogue: MLP head + argmax (block = one t) =====
  {
    const int t = blk;
    const int sl = w, b = lane;
    const float* qa_t = QA + t * 8192;
    const float* ct1 = CTX + (t + 1) * 8192;
    #pragma unroll
    for (int i = 0; i < 8; ++i) {
      int idx = tid + i * 1024;
      SMf[(idx >> 6) * 65 + (idx & 63)] = qa_t[idx];
      SMf[(128 + (idx >> 6)) * 65 + (idx & 63)] = ct1[idx];
    }
    __syncthreads();
    float a1[16];
    #pragma unroll
    for (int i = 0; i < 16; ++i) a1[i] = 0.f;
    const float* w1 = A.w_mlp1 + (sl * 16) * 256;
    #pragma unroll 2
    for (int k = 0; k < 256; ++k) {
      float xv = SMf[k * 65 + b];
      #pragma unroll
      for (int m2 = 0; m2 < 16; ++m2) a1[m2] = fmaf(w1[m2 * 256 + k], xv, a1[m2]);
    }
    float* ACT = SMf + 16640;
    #pragma unroll
    for (int m2 = 0; m2 < 16; ++m2) {
      float v2 = a1[m2] + A.b_mlp1[sl * 16 + m2];
      ACT[(sl * 16 + m2) * 65 + b] = (v2 >= 0.f) ? v2 : 0.9f * v2;   // LeakyReLU(0.9)
    }
    __syncthreads();
    float y[4] = {0.f, 0.f, 0.f, 0.f};
    const float* w2 = A.w_mlp2 + (sl * 4) * 256;
    #pragma unroll 2
    for (int k = 0; k < 256; ++k) {
      float xv = ACT[k * 65 + b];
      #pragma unroll
      for (int m2 = 0; m2 < 4; ++m2) y[m2] = fmaf(w2[m2 * 256 + k], xv, y[m2]);
    }
    #pragma unroll
    for (int m2 = 0; m2 < 4; ++m2) y[m2] += A.b_mlp2[sl * 4 + m2];
    *(float4*)(out0 + b * 16384 + t * 64 + sl * 4) = make_float4(y[0], y[1], y[2], y[3]);
    __syncthreads();
    float* YB = SMf + 34976;
    #pragma unroll
    for (int m2 = 0; m2 < 4; ++m2) YB[(sl * 4 + m2) * 65 + b] = y[m2];
    __syncthreads();
    if (tid < 64) {
      float best = YB[tid];
      int bi = 0;
      #pragma unroll 1
      for (int v = 1; v < 64; ++v) {
        float val = YB[v * 65 + tid];
        if (val > best) { best = val; bi = v; }   // first-occurrence argmax
      }
      out1[tid * 256 + t] = (float)bi;
    }
  }
}

extern "C" void kernel_launch(void* const* d_in, const int* in_sizes, int n_in,
                              void* d_out, int out_size, void* d_ws, size_t ws_size,
                              hipStream_t stream) {
  if (ws_size < (size_t)WS_TOTAL * 4) return;   // ~93.6 MB scratch
  KArgs a;
  a.enc_key = (const float*)d_in[0];
  a.value   = (const float*)d_in[1];
  a.labels  = (const int*)d_in[2];
  a.seqlens = (const int*)d_in[3];
  a.sos     = (const int*)d_in[4];
  a.w_emb  = (const float*)d_in[6];  a.b_emb  = (const float*)d_in[7];
  a.w_ih0  = (const float*)d_in[8];  a.w_hh0  = (const float*)d_in[9];
  a.b_ih0  = (const float*)d_in[10]; a.b_hh0  = (const float*)d_in[11];
  a.w_ih1  = (const float*)d_in[12]; a.w_hh1  = (const float*)d_in[13];
  a.b_ih1  = (const float*)d_in[14]; a.b_hh1  = (const float*)d_in[15];
  a.w_ih2  = (const float*)d_in[16]; a.w_hh2  = (const float*)d_in[17];
  a.b_ih2  = (const float*)d_in[18]; a.b_hh2  = (const float*)d_in[19];
  a.w_fc   = (const float*)d_in[20]; a.b_fc   = (const float*)d_in[21];
  a.w_mlp1 = (const float*)d_in[22]; a.b_mlp1 = (const float*)d_in[23];
  a.w_mlp2 = (const float*)d_in[24]; a.b_mlp2 = (const float*)d_in[25];
  a.out = (float*)d_out;
  a.ws  = (float*)d_ws;

  int* bar = (int*)((float*)d_ws + OF_BAR);
  hipLaunchKernelGGL(bar_init_kernel, dim3(1), dim3(1024), 0, stream, bar);

  void* args[] = { (void*)&a };
  hipLaunchCooperativeKernel(reinterpret_cast<void*>(dec_kernel),
                             dim3(256), dim3(1024), args, 0, stream);
}